// Round 2
// 557.914 us; speedup vs baseline: 1.1327x; 1.1327x over previous
//
#include <hip/hip_runtime.h>
#include <hip/hip_bf16.h>
#include <cstdint>
#include <cstddef>

#define SEQ 2048
#define DM 2048
#define NHEADS 16
#define HD 128
#define NTOK 8192   // 4*2048
#define BATCH 4

typedef __bf16 bf16_t;
typedef bf16_t bf16x8 __attribute__((ext_vector_type(8)));
typedef float f32x4 __attribute__((ext_vector_type(4)));

__device__ __forceinline__ void async_copy16(const bf16_t* g, bf16_t* l) {
  __builtin_amdgcn_global_load_lds(
      (const __attribute__((address_space(1))) unsigned int*)g,
      (__attribute__((address_space(3))) unsigned int*)l, 16, 0, 0);
}

__device__ __forceinline__ void store_out(float* p, float v)  { *p = v; }
__device__ __forceinline__ void store_out(bf16_t* p, float v) { *p = (bf16_t)v; }

// ---------------- conversion / transpose prep ----------------

__global__ void convert_x_bf16(const float* __restrict__ in, bf16_t* __restrict__ out, int n4) {
  int i = blockIdx.x * 256 + threadIdx.x;
  if (i >= n4) return;
  float4 v = ((const float4*)in)[i];
  union { ushort4 u; bf16_t b[4]; } o;
  o.b[0] = (bf16_t)v.x; o.b[1] = (bf16_t)v.y; o.b[2] = (bf16_t)v.z; o.b[3] = (bf16_t)v.w;
  *(ushort4*)(out + (size_t)i * 4) = o.u;
}

// out (C x R) = transpose of in (R x C), fp32 -> bf16
__global__ void transpose_f32_to_bf16(const float* __restrict__ in, bf16_t* __restrict__ out,
                                      int R, int C) {
  __shared__ float tile[32][33];
  int c0 = blockIdx.x * 32, r0 = blockIdx.y * 32;
  int tx = threadIdx.x & 31, ty = threadIdx.x >> 5;  // 32 x 8
  for (int i = ty; i < 32; i += 8) tile[i][tx] = in[(size_t)(r0 + i) * C + c0 + tx];
  __syncthreads();
  for (int i = ty; i < 32; i += 8) out[(size_t)(c0 + i) * R + r0 + tx] = (bf16_t)tile[tx][i];
}

// ---------------- m97-style GEMM: C = A @ Bt^T + bias ----------------
// A: (M,K) bf16 row-major. Bt: (N,K) bf16 row-major. bias: (N) f32. C: (M,N).
template <typename OutT>
__global__ __launch_bounds__(256) void gemm_bt(const bf16_t* __restrict__ A,
                                               const bf16_t* __restrict__ Bt,
                                               const float* __restrict__ bias,
                                               OutT* __restrict__ C, int M, int N, int K) {
  __shared__ bf16_t As[128 * 32];
  __shared__ bf16_t Bs[128 * 32];
  const int tid = threadIdx.x;
  const int lane = tid & 63;
  const int wv = tid >> 6;
  const int wi = wv >> 1, wj = wv & 1;
  const int quad = lane >> 4, l16 = lane & 15;
  const size_t m0 = (size_t)blockIdx.x * 128, n0 = (size_t)blockIdx.y * 128;

  f32x4 acc[4][4] = {};

  const bf16_t* ag = A + (m0 + (tid >> 2)) * K + (tid & 3) * 8;
  const bf16_t* bg = Bt + (n0 + (tid >> 2)) * K + (tid & 3) * 8;
  bf16_t* asd = As + tid * 8;
  bf16_t* bsd = Bs + tid * 8;
  const int nk = K >> 5;
  for (int kt = 0; kt < nk; kt++) {
    async_copy16(ag, asd);
    async_copy16(ag + (size_t)64 * K, asd + 64 * 32);
    async_copy16(bg, bsd);
    async_copy16(bg + (size_t)64 * K, bsd + 64 * 32);
    ag += 32; bg += 32;
    __syncthreads();
    bf16x8 af[4], bf[4];
#pragma unroll
    for (int mt = 0; mt < 4; mt++)
      af[mt] = *(const bf16x8*)(As + (wi * 64 + mt * 16 + l16) * 32 + quad * 8);
#pragma unroll
    for (int nt = 0; nt < 4; nt++)
      bf[nt] = *(const bf16x8*)(Bs + (wj * 64 + nt * 16 + l16) * 32 + quad * 8);
#pragma unroll
    for (int mt = 0; mt < 4; mt++)
#pragma unroll
      for (int nt = 0; nt < 4; nt++)
        acc[mt][nt] = __builtin_amdgcn_mfma_f32_16x16x32_bf16(af[mt], bf[nt], acc[mt][nt], 0, 0, 0);
    __syncthreads();
  }
#pragma unroll
  for (int nt = 0; nt < 4; nt++) {
    float bb = bias[n0 + wj * 64 + nt * 16 + l16];
#pragma unroll
    for (int mt = 0; mt < 4; mt++) {
      size_t row = m0 + wi * 64 + mt * 16 + quad * 4;
      size_t col = n0 + wj * 64 + nt * 16 + l16;
#pragma unroll
      for (int r = 0; r < 4; r++) store_out(&C[(row + r) * N + col], acc[mt][nt][r] + bb);
    }
  }
}

// ---------------- RoPE ----------------
// freq_i = 10000^(-2i/128) = exp(-i * ln(10000)/64)
#define ROPE_C 0.14391156831212787f
// attention scale folded into Q: 1/sqrt(128) * log2(e)  (softmax via exp2)
#define ATT_SCALE 0.1275174462517703f

__global__ void rope_q_kernel(bf16_t* __restrict__ q) {
  int idx = blockIdx.x * 256 + threadIdx.x;  // one per 8 elems
  int tok = idx >> 8;
  int c0 = (idx & 255) * 8;
  int s = tok & (SEQ - 1);
  int d0 = c0 & (HD - 1);
  union { uint4 u; ushort us[8]; } v;
  v.u = *(const uint4*)(q + (size_t)tok * DM + c0);
  float x[8];
#pragma unroll
  for (int j = 0; j < 8; j++) x[j] = __uint_as_float((uint32_t)v.us[j] << 16);
#pragma unroll
  for (int j = 0; j < 4; j++) {
    int i = (d0 >> 1) + j;
    float fr = __expf(-(float)i * ROPE_C);
    float ang = (float)s * fr;
    float sn, cs; __sincosf(ang, &sn, &cs);
    float o1 = (x[2 * j] * cs - x[2 * j + 1] * sn) * ATT_SCALE;
    float o2 = (x[2 * j] * sn + x[2 * j + 1] * cs) * ATT_SCALE;
    x[2 * j] = o1; x[2 * j + 1] = o2;
  }
  union { uint4 u; ushort us[8]; } w;
#pragma unroll
  for (int j = 0; j < 8; j++) {
    union { float f; uint32_t u; } t; t.f = x[j];
    uint32_t r = (t.u + 0x7fff + ((t.u >> 16) & 1)) >> 16;
    w.us[j] = (ushort)r;
  }
  *(uint4*)(q + (size_t)tok * DM + c0) = w.u;
}

__global__ void rope_kv_kernel(const float* __restrict__ kvf, float* __restrict__ kh,
                               float* __restrict__ vh, bf16_t* __restrict__ kbf) {
  int idx = blockIdx.x * 256 + threadIdx.x;  // NTOK*64 threads, one per K-pair
  int t = idx >> 6;
  int i = idx & 63;
  int s = t & (SEQ - 1);
  const float* base = kvf + (size_t)t * 256;
  float x1 = base[2 * i], x2 = base[2 * i + 1];
  float fr = __expf(-(float)i * ROPE_C);
  float ang = (float)s * fr;
  float sn, cs; __sincosf(ang, &sn, &cs);
  float k1 = x1 * cs - x2 * sn, k2 = x1 * sn + x2 * cs;
  size_t o = (size_t)t * HD + 2 * i;
  kh[o] = k1; kh[o + 1] = k2;
  kbf[o] = (bf16_t)k1; kbf[o + 1] = (bf16_t)k2;
  vh[o] = base[128 + 2 * i];
  vh[o + 1] = base[128 + 2 * i + 1];
}

__global__ void transpose_v_kernel(const float* __restrict__ kvf, bf16_t* __restrict__ vT) {
  __shared__ float tile[32][33];
  int b = blockIdx.z;
  int s0 = blockIdx.x * 32, d0 = blockIdx.y * 32;
  int tx = threadIdx.x & 31, ty = threadIdx.x >> 5;
  for (int i = ty; i < 32; i += 8)
    tile[i][tx] = kvf[(size_t)(b * SEQ + s0 + i) * 256 + 128 + d0 + tx];
  __syncthreads();
  for (int i = ty; i < 32; i += 8)
    vT[(size_t)b * HD * SEQ + (size_t)(d0 + i) * SEQ + s0 + tx] = (bf16_t)tile[tx][i];
}

// ---------------- flash attention (causal MQA), S^T formulation ----------------
// Q: (NTOK, DM) roped bf16, pre-scaled by 1/sqrt(HD)*log2(e). Kb: (NTOK, HD) roped bf16.
// VT: (B, HD, SEQ) bf16. O: (NTOK, DM) bf16.
// Grid (8,16,4): block p handles q-tiles {15-p, p} -> uniform 34 k-tile iterations per
// block (perfect balance, no drain tail). Double-buffered K/V LDS (64 KB -> 2 blocks/CU,
// 512 blocks all resident), prefetch next tile with counted s_waitcnt vmcnt(8) + raw
// s_barrier (never drain to 0 mid-loop). P kept fully in registers: cvt_pk_bf16_f32 +
// permlane32/16_swap reproduce the PV B-fragment without an LDS round-trip.
// No online max/alpha: scores bounded in exp2 domain, softmax shift-invariant.
__global__ __launch_bounds__(256, 2) void flash_attn_kernel(const bf16_t* __restrict__ Q,
                                                            const bf16_t* __restrict__ Kb,
                                                            const bf16_t* __restrict__ VT,
                                                            bf16_t* __restrict__ O) {
  __shared__ bf16_t Ks[2][64 * 128];   // row=k-token (64), 16 chunks of 8, XOR-swizzled
  __shared__ bf16_t Vs[2][64 * 128];   // row=d (128), 8 chunks of 8, XOR-swizzled
  const int tid = threadIdx.x;
  const int lane = tid & 63;
  const int wv = tid >> 6;
  const int quad = lane >> 4, l16 = lane & 15;
  const int pr = blockIdx.x, h = blockIdx.y, b = blockIdx.z;

  const bf16_t* kbase = Kb + (size_t)b * SEQ * HD;
  const bf16_t* vbase = VT + (size_t)b * HD * SEQ;

  int cur = 0;
  // prologue: stage tile 0 into buffer 0 (8 global_load_lds per thread)
#pragma unroll
  for (int i = 0; i < 4; i++) {
    int p = i * 256 + tid;
    int kr = p >> 4, kc = (p & 15) ^ (kr & 15);
    async_copy16(kbase + (size_t)kr * HD + kc * 8, &Ks[0][p * 8]);
    int vr = p >> 3, vc = (p & 7) ^ (vr & 7);
    async_copy16(vbase + (size_t)vr * SEQ + vc * 8, &Vs[0][p * 8]);
  }

#pragma unroll 1
  for (int ph = 0; ph < 2; ph++) {
    const int qt = ph ? pr : 15 - pr;   // block-uniform
    const int nkt = 2 * qt + 2;

    // Q fragments (B-operand layout: n-row = l16, k = quad*8+j)
    bf16x8 qf[2][4];
#pragma unroll
    for (int nt = 0; nt < 2; nt++) {
      size_t qrow = (size_t)b * SEQ + qt * 128 + wv * 32 + nt * 16 + l16;
      const bf16_t* qp = Q + qrow * DM + h * HD + quad * 8;
#pragma unroll
      for (int ks = 0; ks < 4; ks++) qf[nt][ks] = *(const bf16x8*)(qp + ks * 32);
    }

    f32x4 oacc[8][2] = {};          // O^T: rows d = dm*16+quad*4+r, col q = nt*16+l16
    float l2[2] = {0.f, 0.f};

#pragma unroll 1
    for (int kt = 0; kt < nkt; kt++) {
      // B1: all waves done reading buf[cur^1] (previous iteration's compute)
      asm volatile("s_waitcnt lgkmcnt(0)" ::: "memory");
      __builtin_amdgcn_sched_barrier(0);
      __builtin_amdgcn_s_barrier();
      __builtin_amdgcn_sched_barrier(0);

      // prefetch next tile into buf[cur^1]; counted wait: 8 newest stay in flight
      const int has_next = !(ph == 1 && kt == nkt - 1);   // block-uniform
      if (has_next) {
        const int k0n = (kt + 1 < nkt) ? (kt + 1) * 64 : 0;  // phase switch restarts at k=0
        bf16_t* kd = &Ks[cur ^ 1][0];
        bf16_t* vd = &Vs[cur ^ 1][0];
#pragma unroll
        for (int i = 0; i < 4; i++) {
          int p = i * 256 + tid;
          int kr = p >> 4, kc = (p & 15) ^ (kr & 15);
          async_copy16(kbase + (size_t)(k0n + kr) * HD + kc * 8, kd + p * 8);
          int vr = p >> 3, vc = (p & 7) ^ (vr & 7);
          async_copy16(vbase + (size_t)vr * SEQ + k0n + vc * 8, vd + p * 8);
        }
        asm volatile("s_waitcnt vmcnt(8)" ::: "memory");
      } else {
        asm volatile("s_waitcnt vmcnt(0)" ::: "memory");
      }
      __builtin_amdgcn_sched_barrier(0);
      // B2: tile kt visible to all waves
      __builtin_amdgcn_s_barrier();
      __builtin_amdgcn_sched_barrier(0);

      const bf16_t* KsC = &Ks[cur][0];
      const bf16_t* VsC = &Vs[cur][0];

      // S^T[k][q] = K Q^T : rows k (mt), cols q (nt); scale folded into Q
      f32x4 sa[4][2] = {};
#pragma unroll
      for (int ks = 0; ks < 4; ks++) {
        bf16x8 ak[4];
#pragma unroll
        for (int mt = 0; mt < 4; mt++) {
          int row = mt * 16 + l16;
          int c = (ks * 4 + quad) ^ l16;
          ak[mt] = *(const bf16x8*)(KsC + (row * 16 + c) * 8);
        }
        __builtin_amdgcn_s_setprio(1);
#pragma unroll
        for (int mt = 0; mt < 4; mt++)
#pragma unroll
          for (int nt = 0; nt < 2; nt++)
            sa[mt][nt] = __builtin_amdgcn_mfma_f32_16x16x32_bf16(ak[mt], qf[nt][ks], sa[mt][nt], 0, 0, 0);
        __builtin_amdgcn_s_setprio(0);
      }

      // causal mask — only the 2 diagonal tiles need it (uniform branch)
      if (kt >= 2 * qt) {
        const int k0c = kt * 64;
#pragma unroll
        for (int mt = 0; mt < 4; mt++)
#pragma unroll
          for (int nt = 0; nt < 2; nt++) {
            int kg0 = k0c + mt * 16 + quad * 4;
            int qg = qt * 128 + wv * 32 + nt * 16 + l16;
#pragma unroll
            for (int r = 0; r < 4; r++)
              if (kg0 + r > qg) sa[mt][nt][r] = -INFINITY;
          }
      }

      // shift-free softmax + in-register P->bf16 B-fragment assembly.
      // Lane(quad,l16) holds P[k=mt*16+quad*4+r][q=nt*16+l16]. PV B-frag needs
      // P[q=l16][k=ks*32+quad*8+j]. With d0(m)=pk(r0,r1), d1(m)=pk(r2,r3):
      //   (w0,w2) = permlane16_swap(permlane32_swap(d0(2ks), d0(2ks+1)))
      //   (w1,w3) = permlane16_swap(permlane32_swap(d1(2ks), d1(2ks+1)))
      bf16x8 bp[2][2];
#pragma unroll
      for (int nt = 0; nt < 2; nt++) {
        float rs = 0.f;
#pragma unroll
        for (int mt = 0; mt < 4; mt++)
#pragma unroll
          for (int r = 0; r < 4; r++) {
            float pv = exp2f(sa[mt][nt][r]);
            sa[mt][nt][r] = pv;
            rs += pv;
          }
        // cross-quad row-sum, VALU-only (permlane copy trick instead of ds shuffles)
        {
          float a0 = rs, a1 = rs;
          asm("v_permlane16_swap_b32 %0, %1" : "+v"(a0), "+v"(a1));
          rs = a0 + a1;
          float c0 = rs, c1 = rs;
          asm("v_permlane32_swap_b32 %0, %1" : "+v"(c0), "+v"(c1));
          rs = c0 + c1;
        }
        l2[nt] += rs;

        uint32_t d0[4], d1[4];
#pragma unroll
        for (int m = 0; m < 4; m++) {
          asm("v_cvt_pk_bf16_f32 %0, %1, %2" : "=v"(d0[m]) : "v"(sa[m][nt][0]), "v"(sa[m][nt][1]));
          asm("v_cvt_pk_bf16_f32 %0, %1, %2" : "=v"(d1[m]) : "v"(sa[m][nt][2]), "v"(sa[m][nt][3]));
        }
#pragma unroll
        for (int ks = 0; ks < 2; ks++) {
          uint32_t w0 = d0[2 * ks], w2 = d0[2 * ks + 1];
          uint32_t w1 = d1[2 * ks], w3 = d1[2 * ks + 1];
          asm("v_permlane32_swap_b32 %0, %1" : "+v"(w0), "+v"(w2));
          asm("v_permlane16_swap_b32 %0, %1" : "+v"(w0), "+v"(w2));
          asm("v_permlane32_swap_b32 %0, %1" : "+v"(w1), "+v"(w3));
          asm("v_permlane16_swap_b32 %0, %1" : "+v"(w1), "+v"(w3));
          union { uint32_t u[4]; bf16x8 v; } pk_;
          pk_.u[0] = w0; pk_.u[1] = w1; pk_.u[2] = w2; pk_.u[3] = w3;
          bp[nt][ks] = pk_.v;
        }
      }

      // O^T += V^T P^T : A = V^T rows (d, k), B = P rows (q, k)
#pragma unroll
      for (int ks = 0; ks < 2; ks++)
#pragma unroll
        for (int dm = 0; dm < 8; dm++) {
          int row = dm * 16 + l16;
          int c = (ks * 4 + quad) ^ (row & 7);
          bf16x8 av = *(const bf16x8*)(VsC + (row * 8 + c) * 8);
          __builtin_amdgcn_s_setprio(1);
#pragma unroll
          for (int nt = 0; nt < 2; nt++)
            oacc[dm][nt] = __builtin_amdgcn_mfma_f32_16x16x32_bf16(av, bp[nt][ks], oacc[dm][nt], 0, 0, 0);
          __builtin_amdgcn_s_setprio(0);
        }

      cur ^= 1;
    }

    // epilogue for this q-tile: O^T / l -> O (pack 4 consecutive d into one 8B store)
    float inv[2];
#pragma unroll
    for (int nt = 0; nt < 2; nt++) inv[nt] = 1.f / l2[nt];
#pragma unroll
    for (int dm = 0; dm < 8; dm++)
#pragma unroll
      for (int nt = 0; nt < 2; nt++) {
        size_t row = (size_t)b * SEQ + qt * 128 + wv * 32 + nt * 16 + l16;
        size_t col = (size_t)h * HD + dm * 16 + quad * 4;
        union { ushort4 u; bf16_t bb[4]; } pk;
#pragma unroll
        for (int r = 0; r < 4; r++) pk.bb[r] = (bf16_t)(oacc[dm][nt][r] * inv[nt]);
        *(ushort4*)(O + row * DM + col) = pk.u;
      }
  }
}

// ---------------- launch ----------------

extern "C" void kernel_launch(void* const* d_in, const int* in_sizes, int n_in,
                              void* d_out, int out_size, void* d_ws, size_t ws_size,
                              hipStream_t stream) {
  const float* x  = (const float*)d_in[0];
  const float* wq = (const float*)d_in[1];
  const float* bq = (const float*)d_in[2];
  const float* wk = (const float*)d_in[3];
  const float* bk = (const float*)d_in[4];
  const float* wv = (const float*)d_in[5];
  const float* bv = (const float*)d_in[6];
  const float* wo = (const float*)d_in[7];
  const float* bo = (const float*)d_in[8];
  char* ws = (char*)d_ws;

  bf16_t* xbf  = (bf16_t*)(ws);                 // 33.5 MB  (reused as attn later)
  bf16_t* qbf  = (bf16_t*)(ws + 33554432ull);   // 33.5 MB
  bf16_t* wqT  = (bf16_t*)(ws + 67108864ull);   // 8.4 MB
  bf16_t* woT  = (bf16_t*)(ws + 75497472ull);   // 8.4 MB
  bf16_t* wkvT = (bf16_t*)(ws + 83886080ull);   // 1 MB
  float*  kvf  = (float* )(ws + 84934656ull);   // 8.4 MB
  bf16_t* kbf  = (bf16_t*)(ws + 93323264ull);   // 2 MB
  bf16_t* vT   = (bf16_t*)(ws + 95420416ull);   // 2 MB
  float*  bkv  = (float* )(ws + 97517568ull);   // 1 KB
  bf16_t* attn = xbf;  // alias: x_bf16 dead after the two input GEMMs

  float* out = (float*)d_out;
  float* kh  = out + 16777216ull;
  float* vh  = kh + 1048576ull;

  hipMemcpyAsync(bkv,       bk, 128 * sizeof(float), hipMemcpyDeviceToDevice, stream);
  hipMemcpyAsync(bkv + 128, bv, 128 * sizeof(float), hipMemcpyDeviceToDevice, stream);

  convert_x_bf16<<<16384, 256, 0, stream>>>(x, xbf, 4194304);
  transpose_f32_to_bf16<<<dim3(64, 64), 256, 0, stream>>>(wq, wqT, 2048, 2048);
  transpose_f32_to_bf16<<<dim3(64, 64), 256, 0, stream>>>(wo, woT, 2048, 2048);
  transpose_f32_to_bf16<<<dim3(4, 64), 256, 0, stream>>>(wk, wkvT, 2048, 128);
  transpose_f32_to_bf16<<<dim3(4, 64), 256, 0, stream>>>(wv, wkvT + 128 * 2048, 2048, 128);

  gemm_bt<bf16_t><<<dim3(64, 16), 256, 0, stream>>>(xbf, wqT, bq, qbf, 8192, 2048, 2048);
  gemm_bt<float ><<<dim3(64, 2),  256, 0, stream>>>(xbf, wkvT, bkv, kvf, 8192, 256, 2048);

  rope_q_kernel<<<8192, 256, 0, stream>>>(qbf);
  rope_kv_kernel<<<2048, 256, 0, stream>>>(kvf, kh, vh, kbf);
  transpose_v_kernel<<<dim3(64, 4, 4), 256, 0, stream>>>(kvf, vT);

  flash_attn_kernel<<<dim3(8, 16, 4), 256, 0, stream>>>(qbf, kbf, vT, attn);

  gemm_bt<float><<<dim3(64, 16), 256, 0, stream>>>(attn, woT, bo, out, 8192, 2048, 2048);
}

// Round 3
// 485.425 us; speedup vs baseline: 1.3019x; 1.1493x over previous
//
#include <hip/hip_runtime.h>
#include <hip/hip_bf16.h>
#include <cstdint>
#include <cstddef>

#define SEQ 2048
#define DM 2048
#define NHEADS 16
#define HD 128
#define NTOK 8192   // 4*2048
#define BATCH 4

typedef __bf16 bf16_t;
typedef bf16_t bf16x8 __attribute__((ext_vector_type(8)));
typedef float f32x4 __attribute__((ext_vector_type(4)));

__device__ __forceinline__ void async_copy16(const bf16_t* g, bf16_t* l) {
  __builtin_amdgcn_global_load_lds(
      (const __attribute__((address_space(1))) unsigned int*)g,
      (__attribute__((address_space(3))) unsigned int*)l, 16, 0, 0);
}

__device__ __forceinline__ void store_out(float* p, float v)  { *p = v; }
__device__ __forceinline__ void store_out(bf16_t* p, float v) { *p = (bf16_t)v; }

#define SB  __builtin_amdgcn_sched_barrier(0)
#define BAR __builtin_amdgcn_s_barrier()
#define LGKM0 asm volatile("s_waitcnt lgkmcnt(0)" ::: "memory")

// ---------------- conversion / transpose prep ----------------

__global__ void convert_x_bf16(const float* __restrict__ in, bf16_t* __restrict__ out, int n4) {
  int i = blockIdx.x * 256 + threadIdx.x;
  if (i >= n4) return;
  float4 v = ((const float4*)in)[i];
  union { ushort4 u; bf16_t b[4]; } o;
  o.b[0] = (bf16_t)v.x; o.b[1] = (bf16_t)v.y; o.b[2] = (bf16_t)v.z; o.b[3] = (bf16_t)v.w;
  *(ushort4*)(out + (size_t)i * 4) = o.u;
}

// out (C x R) = transpose of in (R x C), fp32 -> bf16
__global__ void transpose_f32_to_bf16(const float* __restrict__ in, bf16_t* __restrict__ out,
                                      int R, int C) {
  __shared__ float tile[32][33];
  int c0 = blockIdx.x * 32, r0 = blockIdx.y * 32;
  int tx = threadIdx.x & 31, ty = threadIdx.x >> 5;  // 32 x 8
  for (int i = ty; i < 32; i += 8) tile[i][tx] = in[(size_t)(r0 + i) * C + c0 + tx];
  __syncthreads();
  for (int i = ty; i < 32; i += 8) out[(size_t)(c0 + i) * R + r0 + tx] = (bf16_t)tile[tx][i];
}

// ---------------- m97-style GEMM (kept for the small KV projection) ----------------
template <typename OutT>
__global__ __launch_bounds__(256) void gemm_bt(const bf16_t* __restrict__ A,
                                               const bf16_t* __restrict__ Bt,
                                               const float* __restrict__ bias,
                                               OutT* __restrict__ C, int M, int N, int K) {
  __shared__ bf16_t As[128 * 32];
  __shared__ bf16_t Bs[128 * 32];
  const int tid = threadIdx.x;
  const int lane = tid & 63;
  const int wv = tid >> 6;
  const int wi = wv >> 1, wj = wv & 1;
  const int quad = lane >> 4, l16 = lane & 15;
  const size_t m0 = (size_t)blockIdx.x * 128, n0 = (size_t)blockIdx.y * 128;

  f32x4 acc[4][4] = {};

  const bf16_t* ag = A + (m0 + (tid >> 2)) * K + (tid & 3) * 8;
  const bf16_t* bg = Bt + (n0 + (tid >> 2)) * K + (tid & 3) * 8;
  bf16_t* asd = As + tid * 8;
  bf16_t* bsd = Bs + tid * 8;
  const int nk = K >> 5;
  for (int kt = 0; kt < nk; kt++) {
    async_copy16(ag, asd);
    async_copy16(ag + (size_t)64 * K, asd + 64 * 32);
    async_copy16(bg, bsd);
    async_copy16(bg + (size_t)64 * K, bsd + 64 * 32);
    ag += 32; bg += 32;
    __syncthreads();
    bf16x8 af[4], bf[4];
#pragma unroll
    for (int mt = 0; mt < 4; mt++)
      af[mt] = *(const bf16x8*)(As + (wi * 64 + mt * 16 + l16) * 32 + quad * 8);
#pragma unroll
    for (int nt = 0; nt < 4; nt++)
      bf[nt] = *(const bf16x8*)(Bs + (wj * 64 + nt * 16 + l16) * 32 + quad * 8);
#pragma unroll
    for (int mt = 0; mt < 4; mt++)
#pragma unroll
      for (int nt = 0; nt < 4; nt++)
        acc[mt][nt] = __builtin_amdgcn_mfma_f32_16x16x32_bf16(af[mt], bf[nt], acc[mt][nt], 0, 0, 0);
    __syncthreads();
  }
#pragma unroll
  for (int nt = 0; nt < 4; nt++) {
    float bb = bias[n0 + wj * 64 + nt * 16 + l16];
#pragma unroll
    for (int mt = 0; mt < 4; mt++) {
      size_t row = m0 + wi * 64 + mt * 16 + quad * 4;
      size_t col = n0 + wj * 64 + nt * 16 + l16;
#pragma unroll
      for (int r = 0; r < 4; r++) store_out(&C[(row + r) * N + col], acc[mt][nt][r] + bb);
    }
  }
}

// ---------------- 256x256 8-phase GEMM: C = A @ Bt^T + bias ----------------
// A (M,K), Bt (N,K) bf16 row-major, K-major staging for both. N must be 2048
// (bn = g&7). 512 threads = 8 waves (2M x 4N); per-wave C: 128x64 (acc[8][4]).
// LDS 128 KiB dynamic: per operand 4 half-tile slots [2 ktile][2 khalf] of
// 256rows x 32k, super-row XOR swizzle (C' = C ^ (rp&7)) -> linear
// global_load_lds staging with pre-swizzled source, <=2-way-conflict
// ds_read_b128. 8 phases per 2 K-tiles; stage 1 half-tile/phase; counted
// s_waitcnt vmcnt(4) ONLY at phases 4 and 8 (never 0 mid-loop).
// WAR safety: every slot overwrite is separated from its last read by that
// phase's lgkmcnt(0)-before-MFMA plus the trailing barrier.
template <typename OutT>
__global__ __launch_bounds__(512, 2) void gemm256(const bf16_t* __restrict__ A,
                                                  const bf16_t* __restrict__ Bt,
                                                  const float* __restrict__ bias,
                                                  OutT* __restrict__ C, int M, int N, int K) {
  extern __shared__ char smem_raw[];
  bf16_t* As_ = (bf16_t*)smem_raw;          // 2 slots x 2 kh x 8192 el = 64 KiB
  bf16_t* Bs_ = As_ + 32768;                // same, 64 KiB

  const int tid = threadIdx.x;
  const int lane = tid & 63;
  const int wv = tid >> 6;
  const int wr = wv >> 2, wc = wv & 3;
  const int quad = lane >> 4, l16 = lane & 15;

  // XCD-aware swizzle: 256 blocks = 8 XCDs x 32; each XCD: 4 bm-panels x all 8 bn.
  const int bid = blockIdx.x;
  const int g = (bid & 7) * 32 + (bid >> 3);
  const size_t m0 = (size_t)(g >> 3) * 256;
  const size_t n0 = (size_t)(g & 7) * 256;

  // staging source precompute (inverse swizzle applied to GLOBAL address)
  auto mkrow = [](int s) { int rp = s >> 3; int Cc = (s & 7) ^ (rp & 7); return rp * 2 + (Cc >> 2); };
  auto mkkc  = [](int s) { int rp = s >> 3; int Cc = (s & 7) ^ (rp & 7); return (Cc & 3) * 8; };
  const bf16_t* pA0 = A  + (size_t)(m0 + mkrow(tid)) * K + mkkc(tid);
  const bf16_t* pA1 = A  + (size_t)(m0 + mkrow(tid + 512)) * K + mkkc(tid + 512);
  const bf16_t* pB0 = Bt + (size_t)(n0 + mkrow(tid)) * K + mkkc(tid);
  const bf16_t* pB1 = Bt + (size_t)(n0 + mkrow(tid + 512)) * K + mkkc(tid + 512);

#define STAGE_A(SLOT, KH, KT) do { \
    async_copy16(pA0 + (size_t)(KT) * 64 + (KH) * 32, As_ + (SLOT) * 16384 + (KH) * 8192 + tid * 8); \
    async_copy16(pA1 + (size_t)(KT) * 64 + (KH) * 32, As_ + (SLOT) * 16384 + (KH) * 8192 + (tid + 512) * 8); \
  } while (0)
#define STAGE_B(SLOT, KH, KT) do { \
    async_copy16(pB0 + (size_t)(KT) * 64 + (KH) * 32, Bs_ + (SLOT) * 16384 + (KH) * 8192 + tid * 8); \
    async_copy16(pB1 + (size_t)(KT) * 64 + (KH) * 32, Bs_ + (SLOT) * 16384 + (KH) * 8192 + (tid + 512) * 8); \
  } while (0)

  // ds_read fragment offsets (elements within one 8192-el half-buffer)
  int aoffs[8], boffs[4];
#pragma unroll
  for (int mi = 0; mi < 8; mi++) {
    int row = wr * 128 + mi * 16 + l16;
    int rp = row >> 1, Cc = (row & 1) * 4 + quad;
    aoffs[mi] = rp * 64 + (Cc ^ (rp & 7)) * 8;
  }
#pragma unroll
  for (int ni = 0; ni < 4; ni++) {
    int row = wc * 64 + ni * 16 + l16;
    int rp = row >> 1, Cc = (row & 1) * 4 + quad;
    boffs[ni] = rp * 64 + (Cc ^ (rp & 7)) * 8;
  }

  f32x4 acc[8][4] = {};
  bf16x8 afr[8], b0, b1;

#define LOAD_A(SLOT, KS) do { _Pragma("unroll") \
    for (int mi = 0; mi < 8; mi++) afr[mi] = *(const bf16x8*)(As_ + (SLOT) * 16384 + (KS) * 8192 + aoffs[mi]); \
  } while (0)
#define LOAD_B2(SLOT, KS, NF0) do { \
    b0 = *(const bf16x8*)(Bs_ + (SLOT) * 16384 + (KS) * 8192 + boffs[NF0]); \
    b1 = *(const bf16x8*)(Bs_ + (SLOT) * 16384 + (KS) * 8192 + boffs[(NF0) + 1]); \
  } while (0)
#define MFMA16(NF0) do { __builtin_amdgcn_s_setprio(1); _Pragma("unroll") \
    for (int mi = 0; mi < 8; mi++) { \
      acc[mi][NF0] = __builtin_amdgcn_mfma_f32_16x16x32_bf16(afr[mi], b0, acc[mi][NF0], 0, 0, 0); \
      acc[mi][(NF0) + 1] = __builtin_amdgcn_mfma_f32_16x16x32_bf16(afr[mi], b1, acc[mi][(NF0) + 1], 0, 0, 0); \
    } __builtin_amdgcn_s_setprio(0); } while (0)

  const int NI = K >> 7;  // iterations of 2 K-tiles

  // prologue: klo(0), khi(0), klo(1); drain; barrier
  STAGE_A(0, 0, 0); STAGE_B(0, 0, 0);
  STAGE_A(0, 1, 0); STAGE_B(0, 1, 0);
  STAGE_A(1, 0, 1); STAGE_B(1, 0, 1);
  asm volatile("s_waitcnt vmcnt(0)" ::: "memory");
  SB; BAR; SB;

#pragma unroll 1
  for (int j = 0; j < NI; j++) {
    const int last = (j == NI - 1);
    // ph1: tile 2j ks0, nf 0-1 | stage A-khi(2j+1)
    LOAD_A(0, 0); LOAD_B2(0, 0, 0);
    STAGE_A(1, 1, 2 * j + 1);
    SB; BAR; LGKM0; SB; MFMA16(0); SB; BAR;
    // ph2: ks0 nf 2-3 | stage B-khi(2j+1)
    LOAD_B2(0, 0, 2);
    STAGE_B(1, 1, 2 * j + 1);
    SB; BAR; LGKM0; SB; MFMA16(2); SB; BAR;
    // ph3: ks1 nf 0-1 | stage A-klo(2j+2)
    LOAD_A(0, 1); LOAD_B2(0, 1, 0);
    if (!last) STAGE_A(0, 0, 2 * j + 2);
    SB; BAR; LGKM0; SB; MFMA16(0); SB; BAR;
    // ph4: ks1 nf 2-3 | stage B-klo(2j+2) | counted wait
    LOAD_B2(0, 1, 2);
    if (!last) STAGE_B(0, 0, 2 * j + 2);
    SB;
    if (!last) { asm volatile("s_waitcnt vmcnt(4)" ::: "memory"); }
    else       { asm volatile("s_waitcnt vmcnt(0)" ::: "memory"); }
    BAR; LGKM0; SB; MFMA16(2); SB; BAR;
    // ph5: tile 2j+1 ks0 nf 0-1 | stage A-khi(2j+2)
    LOAD_A(1, 0); LOAD_B2(1, 0, 0);
    if (!last) STAGE_A(0, 1, 2 * j + 2);
    SB; BAR; LGKM0; SB; MFMA16(0); SB; BAR;
    // ph6: ks0 nf 2-3 | stage B-khi(2j+2)
    LOAD_B2(1, 0, 2);
    if (!last) STAGE_B(0, 1, 2 * j + 2);
    SB; BAR; LGKM0; SB; MFMA16(2); SB; BAR;
    // ph7: ks1 nf 0-1 | stage A-klo(2j+3)
    LOAD_A(1, 1); LOAD_B2(1, 1, 0);
    if (!last) STAGE_A(1, 0, 2 * j + 3);
    SB; BAR; LGKM0; SB; MFMA16(0); SB; BAR;
    // ph8: ks1 nf 2-3 | stage B-klo(2j+3) | counted wait
    LOAD_B2(1, 1, 2);
    if (!last) STAGE_B(1, 0, 2 * j + 3);
    SB;
    if (!last) { asm volatile("s_waitcnt vmcnt(4)" ::: "memory"); }
    else       { asm volatile("s_waitcnt vmcnt(0)" ::: "memory"); }
    BAR; LGKM0; SB; MFMA16(2); SB; BAR;
  }

  // epilogue
#pragma unroll
  for (int ni = 0; ni < 4; ni++) {
    size_t col = n0 + wc * 64 + ni * 16 + l16;
    float bb = bias[col];
#pragma unroll
    for (int mi = 0; mi < 8; mi++) {
      size_t row = m0 + wr * 128 + mi * 16 + quad * 4;
#pragma unroll
      for (int r = 0; r < 4; r++) store_out(&C[(row + r) * N + col], acc[mi][ni][r] + bb);
    }
  }
#undef STAGE_A
#undef STAGE_B
#undef LOAD_A
#undef LOAD_B2
#undef MFMA16
}

// ---------------- RoPE ----------------
// freq_i = 10000^(-2i/128) = exp(-i * ln(10000)/64)
#define ROPE_C 0.14391156831212787f
// attention scale folded into Q: 1/sqrt(128) * log2(e)  (softmax via exp2)
#define ATT_SCALE 0.1275174462517703f

__global__ void rope_q_kernel(bf16_t* __restrict__ q) {
  int idx = blockIdx.x * 256 + threadIdx.x;  // one per 8 elems
  int tok = idx >> 8;
  int c0 = (idx & 255) * 8;
  int s = tok & (SEQ - 1);
  int d0 = c0 & (HD - 1);
  union { uint4 u; ushort us[8]; } v;
  v.u = *(const uint4*)(q + (size_t)tok * DM + c0);
  float x[8];
#pragma unroll
  for (int j = 0; j < 8; j++) x[j] = __uint_as_float((uint32_t)v.us[j] << 16);
#pragma unroll
  for (int j = 0; j < 4; j++) {
    int i = (d0 >> 1) + j;
    float fr = __expf(-(float)i * ROPE_C);
    float ang = (float)s * fr;
    float sn, cs; __sincosf(ang, &sn, &cs);
    float o1 = (x[2 * j] * cs - x[2 * j + 1] * sn) * ATT_SCALE;
    float o2 = (x[2 * j] * sn + x[2 * j + 1] * cs) * ATT_SCALE;
    x[2 * j] = o1; x[2 * j + 1] = o2;
  }
  union { uint4 u; ushort us[8]; } w;
#pragma unroll
  for (int j = 0; j < 8; j++) {
    union { float f; uint32_t u; } t; t.f = x[j];
    uint32_t r = (t.u + 0x7fff + ((t.u >> 16) & 1)) >> 16;
    w.us[j] = (ushort)r;
  }
  *(uint4*)(q + (size_t)tok * DM + c0) = w.u;
}

__global__ void rope_kv_kernel(const float* __restrict__ kvf, float* __restrict__ kh,
                               float* __restrict__ vh, bf16_t* __restrict__ kbf) {
  int idx = blockIdx.x * 256 + threadIdx.x;  // NTOK*64 threads, one per K-pair
  int t = idx >> 6;
  int i = idx & 63;
  int s = t & (SEQ - 1);
  const float* base = kvf + (size_t)t * 256;
  float x1 = base[2 * i], x2 = base[2 * i + 1];
  float fr = __expf(-(float)i * ROPE_C);
  float ang = (float)s * fr;
  float sn, cs; __sincosf(ang, &sn, &cs);
  float k1 = x1 * cs - x2 * sn, k2 = x1 * sn + x2 * cs;
  size_t o = (size_t)t * HD + 2 * i;
  kh[o] = k1; kh[o + 1] = k2;
  kbf[o] = (bf16_t)k1; kbf[o + 1] = (bf16_t)k2;
  vh[o] = base[128 + 2 * i];
  vh[o + 1] = base[128 + 2 * i + 1];
}

__global__ void transpose_v_kernel(const float* __restrict__ kvf, bf16_t* __restrict__ vT) {
  __shared__ float tile[32][33];
  int b = blockIdx.z;
  int s0 = blockIdx.x * 32, d0 = blockIdx.y * 32;
  int tx = threadIdx.x & 31, ty = threadIdx.x >> 5;
  for (int i = ty; i < 32; i += 8)
    tile[i][tx] = kvf[(size_t)(b * SEQ + s0 + i) * 256 + 128 + d0 + tx];
  __syncthreads();
  for (int i = ty; i < 32; i += 8)
    vT[(size_t)b * HD * SEQ + (size_t)(d0 + i) * SEQ + s0 + tx] = (bf16_t)tile[tx][i];
}

// ---------------- flash attention (causal MQA), S^T formulation ----------------
// (unchanged from the verified round-2 kernel: 121.5 us, 0 bank conflicts)
__global__ __launch_bounds__(256, 2) void flash_attn_kernel(const bf16_t* __restrict__ Q,
                                                            const bf16_t* __restrict__ Kb,
                                                            const bf16_t* __restrict__ VT,
                                                            bf16_t* __restrict__ O) {
  __shared__ bf16_t Ks[2][64 * 128];   // row=k-token (64), 16 chunks of 8, XOR-swizzled
  __shared__ bf16_t Vs[2][64 * 128];   // row=d (128), 8 chunks of 8, XOR-swizzled
  const int tid = threadIdx.x;
  const int lane = tid & 63;
  const int wv = tid >> 6;
  const int quad = lane >> 4, l16 = lane & 15;
  const int pr = blockIdx.x, h = blockIdx.y, b = blockIdx.z;

  const bf16_t* kbase = Kb + (size_t)b * SEQ * HD;
  const bf16_t* vbase = VT + (size_t)b * HD * SEQ;

  int cur = 0;
#pragma unroll
  for (int i = 0; i < 4; i++) {
    int p = i * 256 + tid;
    int kr = p >> 4, kc = (p & 15) ^ (kr & 15);
    async_copy16(kbase + (size_t)kr * HD + kc * 8, &Ks[0][p * 8]);
    int vr = p >> 3, vc = (p & 7) ^ (vr & 7);
    async_copy16(vbase + (size_t)vr * SEQ + vc * 8, &Vs[0][p * 8]);
  }

#pragma unroll 1
  for (int ph = 0; ph < 2; ph++) {
    const int qt = ph ? pr : 15 - pr;   // block-uniform
    const int nkt = 2 * qt + 2;

    bf16x8 qf[2][4];
#pragma unroll
    for (int nt = 0; nt < 2; nt++) {
      size_t qrow = (size_t)b * SEQ + qt * 128 + wv * 32 + nt * 16 + l16;
      const bf16_t* qp = Q + qrow * DM + h * HD + quad * 8;
#pragma unroll
      for (int ks = 0; ks < 4; ks++) qf[nt][ks] = *(const bf16x8*)(qp + ks * 32);
    }

    f32x4 oacc[8][2] = {};
    float l2[2] = {0.f, 0.f};

#pragma unroll 1
    for (int kt = 0; kt < nkt; kt++) {
      asm volatile("s_waitcnt lgkmcnt(0)" ::: "memory");
      SB; BAR; SB;

      const int has_next = !(ph == 1 && kt == nkt - 1);
      if (has_next) {
        const int k0n = (kt + 1 < nkt) ? (kt + 1) * 64 : 0;
        bf16_t* kd = &Ks[cur ^ 1][0];
        bf16_t* vd = &Vs[cur ^ 1][0];
#pragma unroll
        for (int i = 0; i < 4; i++) {
          int p = i * 256 + tid;
          int kr = p >> 4, kc = (p & 15) ^ (kr & 15);
          async_copy16(kbase + (size_t)(k0n + kr) * HD + kc * 8, kd + p * 8);
          int vr = p >> 3, vc = (p & 7) ^ (vr & 7);
          async_copy16(vbase + (size_t)vr * SEQ + k0n + vc * 8, vd + p * 8);
        }
        asm volatile("s_waitcnt vmcnt(8)" ::: "memory");
      } else {
        asm volatile("s_waitcnt vmcnt(0)" ::: "memory");
      }
      SB; BAR; SB;

      const bf16_t* KsC = &Ks[cur][0];
      const bf16_t* VsC = &Vs[cur][0];

      f32x4 sa[4][2] = {};
#pragma unroll
      for (int ks = 0; ks < 4; ks++) {
        bf16x8 ak[4];
#pragma unroll
        for (int mt = 0; mt < 4; mt++) {
          int row = mt * 16 + l16;
          int c = (ks * 4 + quad) ^ l16;
          ak[mt] = *(const bf16x8*)(KsC + (row * 16 + c) * 8);
        }
        __builtin_amdgcn_s_setprio(1);
#pragma unroll
        for (int mt = 0; mt < 4; mt++)
#pragma unroll
          for (int nt = 0; nt < 2; nt++)
            sa[mt][nt] = __builtin_amdgcn_mfma_f32_16x16x32_bf16(ak[mt], qf[nt][ks], sa[mt][nt], 0, 0, 0);
        __builtin_amdgcn_s_setprio(0);
      }

      if (kt >= 2 * qt) {
        const int k0c = kt * 64;
#pragma unroll
        for (int mt = 0; mt < 4; mt++)
#pragma unroll
          for (int nt = 0; nt < 2; nt++) {
            int kg0 = k0c + mt * 16 + quad * 4;
            int qg = qt * 128 + wv * 32 + nt * 16 + l16;
#pragma unroll
            for (int r = 0; r < 4; r++)
              if (kg0 + r > qg) sa[mt][nt][r] = -INFINITY;
          }
      }

      bf16x8 bp[2][2];
#pragma unroll
      for (int nt = 0; nt < 2; nt++) {
        float rs = 0.f;
#pragma unroll
        for (int mt = 0; mt < 4; mt++)
#pragma unroll
          for (int r = 0; r < 4; r++) {
            float pv = exp2f(sa[mt][nt][r]);
            sa[mt][nt][r] = pv;
            rs += pv;
          }
        {
          float a0 = rs, a1 = rs;
          asm("v_permlane16_swap_b32 %0, %1" : "+v"(a0), "+v"(a1));
          rs = a0 + a1;
          float c0 = rs, c1 = rs;
          asm("v_permlane32_swap_b32 %0, %1" : "+v"(c0), "+v"(c1));
          rs = c0 + c1;
        }
        l2[nt] += rs;

        uint32_t d0[4], d1[4];
#pragma unroll
        for (int m = 0; m < 4; m++) {
          asm("v_cvt_pk_bf16_f32 %0, %1, %2" : "=v"(d0[m]) : "v"(sa[m][nt][0]), "v"(sa[m][nt][1]));
          asm("v_cvt_pk_bf16_f32 %0, %1, %2" : "=v"(d1[m]) : "v"(sa[m][nt][2]), "v"(sa[m][nt][3]));
        }
#pragma unroll
        for (int ks = 0; ks < 2; ks++) {
          uint32_t w0 = d0[2 * ks], w2 = d0[2 * ks + 1];
          uint32_t w1 = d1[2 * ks], w3 = d1[2 * ks + 1];
          asm("v_permlane32_swap_b32 %0, %1" : "+v"(w0), "+v"(w2));
          asm("v_permlane16_swap_b32 %0, %1" : "+v"(w0), "+v"(w2));
          asm("v_permlane32_swap_b32 %0, %1" : "+v"(w1), "+v"(w3));
          asm("v_permlane16_swap_b32 %0, %1" : "+v"(w1), "+v"(w3));
          union { uint32_t u[4]; bf16x8 v; } pk_;
          pk_.u[0] = w0; pk_.u[1] = w1; pk_.u[2] = w2; pk_.u[3] = w3;
          bp[nt][ks] = pk_.v;
        }
      }

#pragma unroll
      for (int ks = 0; ks < 2; ks++)
#pragma unroll
        for (int dm = 0; dm < 8; dm++) {
          int row = dm * 16 + l16;
          int c = (ks * 4 + quad) ^ (row & 7);
          bf16x8 av = *(const bf16x8*)(VsC + (row * 8 + c) * 8);
          __builtin_amdgcn_s_setprio(1);
#pragma unroll
          for (int nt = 0; nt < 2; nt++)
            oacc[dm][nt] = __builtin_amdgcn_mfma_f32_16x16x32_bf16(av, bp[nt][ks], oacc[dm][nt], 0, 0, 0);
          __builtin_amdgcn_s_setprio(0);
        }

      cur ^= 1;
    }

    float inv[2];
#pragma unroll
    for (int nt = 0; nt < 2; nt++) inv[nt] = 1.f / l2[nt];
#pragma unroll
    for (int dm = 0; dm < 8; dm++)
#pragma unroll
      for (int nt = 0; nt < 2; nt++) {
        size_t row = (size_t)b * SEQ + qt * 128 + wv * 32 + nt * 16 + l16;
        size_t col = (size_t)h * HD + dm * 16 + quad * 4;
        union { ushort4 u; bf16_t bb[4]; } pk;
#pragma unroll
        for (int r = 0; r < 4; r++) pk.bb[r] = (bf16_t)(oacc[dm][nt][r] * inv[nt]);
        *(ushort4*)(O + row * DM + col) = pk.u;
      }
  }
}

// ---------------- launch ----------------

extern "C" void kernel_launch(void* const* d_in, const int* in_sizes, int n_in,
                              void* d_out, int out_size, void* d_ws, size_t ws_size,
                              hipStream_t stream) {
  const float* x  = (const float*)d_in[0];
  const float* wq = (const float*)d_in[1];
  const float* bq = (const float*)d_in[2];
  const float* wk = (const float*)d_in[3];
  const float* bk = (const float*)d_in[4];
  const float* wv = (const float*)d_in[5];
  const float* bv = (const float*)d_in[6];
  const float* wo = (const float*)d_in[7];
  const float* bo = (const float*)d_in[8];
  char* ws = (char*)d_ws;

  bf16_t* xbf  = (bf16_t*)(ws);                 // 33.5 MB  (reused as attn later)
  bf16_t* qbf  = (bf16_t*)(ws + 33554432ull);   // 33.5 MB
  bf16_t* wqT  = (bf16_t*)(ws + 67108864ull);   // 8.4 MB
  bf16_t* woT  = (bf16_t*)(ws + 75497472ull);   // 8.4 MB
  bf16_t* wkvT = (bf16_t*)(ws + 83886080ull);   // 1 MB
  float*  kvf  = (float* )(ws + 84934656ull);   // 8.4 MB
  bf16_t* kbf  = (bf16_t*)(ws + 93323264ull);   // 2 MB
  bf16_t* vT   = (bf16_t*)(ws + 95420416ull);   // 2 MB
  float*  bkv  = (float* )(ws + 97517568ull);   // 1 KB
  bf16_t* attn = xbf;  // alias: x_bf16 dead after the two input GEMMs

  float* out = (float*)d_out;
  float* kh  = out + 16777216ull;
  float* vh  = kh + 1048576ull;

  // 128 KiB dynamic LDS opt-in for the 256x256 8-phase GEMM
  hipFuncSetAttribute((const void*)gemm256<bf16_t>, hipFuncAttributeMaxDynamicSharedMemorySize, 131072);
  hipFuncSetAttribute((const void*)gemm256<float>,  hipFuncAttributeMaxDynamicSharedMemorySize, 131072);

  hipMemcpyAsync(bkv,       bk, 128 * sizeof(float), hipMemcpyDeviceToDevice, stream);
  hipMemcpyAsync(bkv + 128, bv, 128 * sizeof(float), hipMemcpyDeviceToDevice, stream);

  convert_x_bf16<<<16384, 256, 0, stream>>>(x, xbf, 4194304);
  transpose_f32_to_bf16<<<dim3(64, 64), 256, 0, stream>>>(wq, wqT, 2048, 2048);
  transpose_f32_to_bf16<<<dim3(64, 64), 256, 0, stream>>>(wo, woT, 2048, 2048);
  transpose_f32_to_bf16<<<dim3(4, 64), 256, 0, stream>>>(wk, wkvT, 2048, 128);
  transpose_f32_to_bf16<<<dim3(4, 64), 256, 0, stream>>>(wv, wkvT + 128 * 2048, 2048, 128);

  gemm256<bf16_t><<<256, 512, 131072, stream>>>(xbf, wqT, bq, qbf, 8192, 2048, 2048);
  gemm_bt<float ><<<dim3(64, 2), 256, 0, stream>>>(xbf, wkvT, bkv, kvf, 8192, 256, 2048);

  rope_q_kernel<<<8192, 256, 0, stream>>>(qbf);
  rope_kv_kernel<<<2048, 256, 0, stream>>>(kvf, kh, vh, kbf);
  transpose_v_kernel<<<dim3(64, 4, 4), 256, 0, stream>>>(kvf, vT);

  flash_attn_kernel<<<dim3(8, 16, 4), 256, 0, stream>>>(qbf, kbf, vT, attn);

  gemm256<float><<<256, 512, 131072, stream>>>(attn, woT, bo, out, 8192, 2048, 2048);
}

// Round 4
// 463.510 us; speedup vs baseline: 1.3634x; 1.0473x over previous
//
#include <hip/hip_runtime.h>
#include <hip/hip_bf16.h>
#include <cstdint>
#include <cstddef>

#define SEQ 2048
#define DM 2048
#define NHEADS 16
#define HD 128
#define NTOK 8192   // 4*2048
#define BATCH 4

typedef __bf16 bf16_t;
typedef bf16_t bf16x8 __attribute__((ext_vector_type(8)));
typedef float f32x4 __attribute__((ext_vector_type(4)));

__device__ __forceinline__ void async_copy16(const bf16_t* g, bf16_t* l) {
  __builtin_amdgcn_global_load_lds(
      (const __attribute__((address_space(1))) unsigned int*)g,
      (__attribute__((address_space(3))) unsigned int*)l, 16, 0, 0);
}

__device__ __forceinline__ void store_out(float* p, float v)  { *p = v; }
__device__ __forceinline__ void store_out(bf16_t* p, float v) { *p = (bf16_t)v; }

__device__ __forceinline__ ushort bf16_rne(float f) {
  union { float f; uint32_t u; } t; t.f = f;
  return (ushort)((t.u + 0x7fff + ((t.u >> 16) & 1)) >> 16);
}

#define SB  __builtin_amdgcn_sched_barrier(0)
#define BAR __builtin_amdgcn_s_barrier()
#define LGKM0 asm volatile("s_waitcnt lgkmcnt(0)" ::: "memory")
#define VM0 asm volatile("s_waitcnt vmcnt(0)" ::: "memory")

// ---------------- conversion / transpose prep ----------------

__global__ void convert_x_bf16(const float* __restrict__ in, bf16_t* __restrict__ out, int n4) {
  int i = blockIdx.x * 256 + threadIdx.x;
  if (i >= n4) return;
  float4 v = ((const float4*)in)[i];
  union { ushort4 u; bf16_t b[4]; } o;
  o.b[0] = (bf16_t)v.x; o.b[1] = (bf16_t)v.y; o.b[2] = (bf16_t)v.z; o.b[3] = (bf16_t)v.w;
  *(ushort4*)(out + (size_t)i * 4) = o.u;
}

// two 2048x2048 transposes (wq, wo) in one launch; blockIdx.z picks the matrix
__global__ void transpose_qo(const float* __restrict__ wq, const float* __restrict__ wo,
                             bf16_t* __restrict__ wqT, bf16_t* __restrict__ woT) {
  __shared__ float tile[32][33];
  const float* in = blockIdx.z ? wo : wq;
  bf16_t* out = blockIdx.z ? woT : wqT;
  int c0 = blockIdx.x * 32, r0 = blockIdx.y * 32;
  int tx = threadIdx.x & 31, ty = threadIdx.x >> 5;  // 32 x 8
  for (int i = ty; i < 32; i += 8) tile[i][tx] = in[(size_t)(r0 + i) * 2048 + c0 + tx];
  __syncthreads();
  for (int i = ty; i < 32; i += 8) out[(size_t)(c0 + i) * 2048 + r0 + tx] = (bf16_t)tile[tx][i];
}

// wk and wv (2048x128) transposed into wkvT (256x2048) in one launch
__global__ void transpose_wkv(const float* __restrict__ wk, const float* __restrict__ wv,
                              bf16_t* __restrict__ wkvT) {
  __shared__ float tile[32][33];
  const float* in = blockIdx.z ? wv : wk;
  bf16_t* out = wkvT + (size_t)blockIdx.z * 128 * 2048;
  int c0 = blockIdx.x * 32, r0 = blockIdx.y * 32;
  int tx = threadIdx.x & 31, ty = threadIdx.x >> 5;
  for (int i = ty; i < 32; i += 8) tile[i][tx] = in[(size_t)(r0 + i) * 128 + c0 + tx];
  __syncthreads();
  for (int i = ty; i < 32; i += 8) out[(size_t)(c0 + i) * 2048 + r0 + tx] = (bf16_t)tile[tx][i];
}

// ---------------- m97-style GEMM (KV projection), dual bias ----------------
__global__ __launch_bounds__(256) void gemm_bt_kv(const bf16_t* __restrict__ A,
                                                  const bf16_t* __restrict__ Bt,
                                                  const float* __restrict__ bk,
                                                  const float* __restrict__ bv,
                                                  float* __restrict__ C, int M, int N, int K) {
  __shared__ bf16_t As[128 * 32];
  __shared__ bf16_t Bs[128 * 32];
  const int tid = threadIdx.x;
  const int lane = tid & 63;
  const int wv = tid >> 6;
  const int wi = wv >> 1, wj = wv & 1;
  const int quad = lane >> 4, l16 = lane & 15;
  const size_t m0 = (size_t)blockIdx.x * 128, n0 = (size_t)blockIdx.y * 128;

  f32x4 acc[4][4] = {};

  const bf16_t* ag = A + (m0 + (tid >> 2)) * K + (tid & 3) * 8;
  const bf16_t* bg = Bt + (n0 + (tid >> 2)) * K + (tid & 3) * 8;
  bf16_t* asd = As + tid * 8;
  bf16_t* bsd = Bs + tid * 8;
  const int nk = K >> 5;
  for (int kt = 0; kt < nk; kt++) {
    async_copy16(ag, asd);
    async_copy16(ag + (size_t)64 * K, asd + 64 * 32);
    async_copy16(bg, bsd);
    async_copy16(bg + (size_t)64 * K, bsd + 64 * 32);
    ag += 32; bg += 32;
    __syncthreads();
    bf16x8 af[4], bf[4];
#pragma unroll
    for (int mt = 0; mt < 4; mt++)
      af[mt] = *(const bf16x8*)(As + (wi * 64 + mt * 16 + l16) * 32 + quad * 8);
#pragma unroll
    for (int nt = 0; nt < 4; nt++)
      bf[nt] = *(const bf16x8*)(Bs + (wj * 64 + nt * 16 + l16) * 32 + quad * 8);
#pragma unroll
    for (int mt = 0; mt < 4; mt++)
#pragma unroll
      for (int nt = 0; nt < 4; nt++)
        acc[mt][nt] = __builtin_amdgcn_mfma_f32_16x16x32_bf16(af[mt], bf[nt], acc[mt][nt], 0, 0, 0);
    __syncthreads();
  }
#pragma unroll
  for (int nt = 0; nt < 4; nt++) {
    size_t col = n0 + wj * 64 + nt * 16 + l16;
    float bb = (col < 128) ? bk[col] : bv[col - 128];
#pragma unroll
    for (int mt = 0; mt < 4; mt++) {
      size_t row = m0 + wi * 64 + mt * 16 + quad * 4;
#pragma unroll
      for (int r = 0; r < 4; r++) C[(row + r) * N + col] = acc[mt][nt][r] + bb;
    }
  }
}

// ---------------- 256x256 8-phase GEMM: C = A @ Bt^T + bias ----------------
// (verified round-3 kernel, unchanged)
template <typename OutT>
__global__ __launch_bounds__(512, 2) void gemm256(const bf16_t* __restrict__ A,
                                                  const bf16_t* __restrict__ Bt,
                                                  const float* __restrict__ bias,
                                                  OutT* __restrict__ C, int M, int N, int K) {
  extern __shared__ char smem_raw[];
  bf16_t* As_ = (bf16_t*)smem_raw;          // 2 slots x 2 kh x 8192 el = 64 KiB
  bf16_t* Bs_ = As_ + 32768;                // same, 64 KiB

  const int tid = threadIdx.x;
  const int lane = tid & 63;
  const int wv = tid >> 6;
  const int wr = wv >> 2, wc = wv & 3;
  const int quad = lane >> 4, l16 = lane & 15;

  const int bid = blockIdx.x;
  const int g = (bid & 7) * 32 + (bid >> 3);
  const size_t m0 = (size_t)(g >> 3) * 256;
  const size_t n0 = (size_t)(g & 7) * 256;

  auto mkrow = [](int s) { int rp = s >> 3; int Cc = (s & 7) ^ (rp & 7); return rp * 2 + (Cc >> 2); };
  auto mkkc  = [](int s) { int rp = s >> 3; int Cc = (s & 7) ^ (rp & 7); return (Cc & 3) * 8; };
  const bf16_t* pA0 = A  + (size_t)(m0 + mkrow(tid)) * K + mkkc(tid);
  const bf16_t* pA1 = A  + (size_t)(m0 + mkrow(tid + 512)) * K + mkkc(tid + 512);
  const bf16_t* pB0 = Bt + (size_t)(n0 + mkrow(tid)) * K + mkkc(tid);
  const bf16_t* pB1 = Bt + (size_t)(n0 + mkrow(tid + 512)) * K + mkkc(tid + 512);

#define STAGE_A(SLOT, KH, KT) do { \
    async_copy16(pA0 + (size_t)(KT) * 64 + (KH) * 32, As_ + (SLOT) * 16384 + (KH) * 8192 + tid * 8); \
    async_copy16(pA1 + (size_t)(KT) * 64 + (KH) * 32, As_ + (SLOT) * 16384 + (KH) * 8192 + (tid + 512) * 8); \
  } while (0)
#define STAGE_B(SLOT, KH, KT) do { \
    async_copy16(pB0 + (size_t)(KT) * 64 + (KH) * 32, Bs_ + (SLOT) * 16384 + (KH) * 8192 + tid * 8); \
    async_copy16(pB1 + (size_t)(KT) * 64 + (KH) * 32, Bs_ + (SLOT) * 16384 + (KH) * 8192 + (tid + 512) * 8); \
  } while (0)

  int aoffs[8], boffs[4];
#pragma unroll
  for (int mi = 0; mi < 8; mi++) {
    int row = wr * 128 + mi * 16 + l16;
    int rp = row >> 1, Cc = (row & 1) * 4 + quad;
    aoffs[mi] = rp * 64 + (Cc ^ (rp & 7)) * 8;
  }
#pragma unroll
  for (int ni = 0; ni < 4; ni++) {
    int row = wc * 64 + ni * 16 + l16;
    int rp = row >> 1, Cc = (row & 1) * 4 + quad;
    boffs[ni] = rp * 64 + (Cc ^ (rp & 7)) * 8;
  }

  f32x4 acc[8][4] = {};
  bf16x8 afr[8], b0, b1;

#define LOAD_A(SLOT, KS) do { _Pragma("unroll") \
    for (int mi = 0; mi < 8; mi++) afr[mi] = *(const bf16x8*)(As_ + (SLOT) * 16384 + (KS) * 8192 + aoffs[mi]); \
  } while (0)
#define LOAD_B2(SLOT, KS, NF0) do { \
    b0 = *(const bf16x8*)(Bs_ + (SLOT) * 16384 + (KS) * 8192 + boffs[NF0]); \
    b1 = *(const bf16x8*)(Bs_ + (SLOT) * 16384 + (KS) * 8192 + boffs[(NF0) + 1]); \
  } while (0)
#define MFMA16(NF0) do { __builtin_amdgcn_s_setprio(1); _Pragma("unroll") \
    for (int mi = 0; mi < 8; mi++) { \
      acc[mi][NF0] = __builtin_amdgcn_mfma_f32_16x16x32_bf16(afr[mi], b0, acc[mi][NF0], 0, 0, 0); \
      acc[mi][(NF0) + 1] = __builtin_amdgcn_mfma_f32_16x16x32_bf16(afr[mi], b1, acc[mi][(NF0) + 1], 0, 0, 0); \
    } __builtin_amdgcn_s_setprio(0); } while (0)

  const int NI = K >> 7;

  STAGE_A(0, 0, 0); STAGE_B(0, 0, 0);
  STAGE_A(0, 1, 0); STAGE_B(0, 1, 0);
  STAGE_A(1, 0, 1); STAGE_B(1, 0, 1);
  VM0;
  SB; BAR; SB;

#pragma unroll 1
  for (int j = 0; j < NI; j++) {
    const int last = (j == NI - 1);
    LOAD_A(0, 0); LOAD_B2(0, 0, 0);
    STAGE_A(1, 1, 2 * j + 1);
    SB; BAR; LGKM0; SB; MFMA16(0); SB; BAR;
    LOAD_B2(0, 0, 2);
    STAGE_B(1, 1, 2 * j + 1);
    SB; BAR; LGKM0; SB; MFMA16(2); SB; BAR;
    LOAD_A(0, 1); LOAD_B2(0, 1, 0);
    if (!last) STAGE_A(0, 0, 2 * j + 2);
    SB; BAR; LGKM0; SB; MFMA16(0); SB; BAR;
    LOAD_B2(0, 1, 2);
    if (!last) STAGE_B(0, 0, 2 * j + 2);
    SB;
    if (!last) { asm volatile("s_waitcnt vmcnt(4)" ::: "memory"); }
    else       { VM0; }
    BAR; LGKM0; SB; MFMA16(2); SB; BAR;
    LOAD_A(1, 0); LOAD_B2(1, 0, 0);
    if (!last) STAGE_A(0, 1, 2 * j + 2);
    SB; BAR; LGKM0; SB; MFMA16(0); SB; BAR;
    LOAD_B2(1, 0, 2);
    if (!last) STAGE_B(0, 1, 2 * j + 2);
    SB; BAR; LGKM0; SB; MFMA16(2); SB; BAR;
    LOAD_A(1, 1); LOAD_B2(1, 1, 0);
    if (!last) STAGE_A(1, 0, 2 * j + 3);
    SB; BAR; LGKM0; SB; MFMA16(0); SB; BAR;
    LOAD_B2(1, 1, 2);
    if (!last) STAGE_B(1, 0, 2 * j + 3);
    SB;
    if (!last) { asm volatile("s_waitcnt vmcnt(4)" ::: "memory"); }
    else       { VM0; }
    BAR; LGKM0; SB; MFMA16(2); SB; BAR;
  }

#pragma unroll
  for (int ni = 0; ni < 4; ni++) {
    size_t col = n0 + wc * 64 + ni * 16 + l16;
    float bb = bias[col];
#pragma unroll
    for (int mi = 0; mi < 8; mi++) {
      size_t row = m0 + wr * 128 + mi * 16 + quad * 4;
#pragma unroll
      for (int r = 0; r < 4; r++) store_out(&C[(row + r) * N + col], acc[mi][ni][r] + bb);
    }
  }
#undef STAGE_A
#undef STAGE_B
#undef LOAD_A
#undef LOAD_B2
#undef MFMA16
}

// ---------------- RoPE ----------------
// freq_i = 10000^(-2i/128) = exp(-i * ln(10000)/64)
#define ROPE_C 0.14391156831212787f
// attention scale folded into Q: 1/sqrt(128) * log2(e)  (softmax via exp2)
#define ATT_SCALE 0.1275174462517703f

// fused: rope K half of kvf -> kh/kbf, copy V half -> vh  (blocks 0..2047)
//        transpose V half -> vT                            (blocks 2048..3071)
__global__ void rope_kv_tv(const float* __restrict__ kvf, float* __restrict__ kh,
                           float* __restrict__ vh, bf16_t* __restrict__ kbf,
                           bf16_t* __restrict__ vT) {
  int bid = blockIdx.x;
  if (bid < 2048) {
    int idx = bid * 256 + threadIdx.x;  // one per K-pair
    int t = idx >> 6;
    int i = idx & 63;
    int s = t & (SEQ - 1);
    const float* base = kvf + (size_t)t * 256;
    float x1 = base[2 * i], x2 = base[2 * i + 1];
    float fr = __expf(-(float)i * ROPE_C);
    float ang = (float)s * fr;
    float sn, cs; __sincosf(ang, &sn, &cs);
    float k1 = x1 * cs - x2 * sn, k2 = x1 * sn + x2 * cs;
    size_t o = (size_t)t * HD + 2 * i;
    kh[o] = k1; kh[o + 1] = k2;
    kbf[o] = (bf16_t)k1; kbf[o + 1] = (bf16_t)k2;
    vh[o] = base[128 + 2 * i];
    vh[o + 1] = base[128 + 2 * i + 1];
  } else {
    __shared__ float tile[32][33];
    int t = bid - 2048;                 // 64 x 4 x 4
    int s0 = (t & 63) * 32, d0 = ((t >> 6) & 3) * 32, b = t >> 8;
    int tx = threadIdx.x & 31, ty = threadIdx.x >> 5;
    for (int i = ty; i < 32; i += 8)
      tile[i][tx] = kvf[(size_t)(b * SEQ + s0 + i) * 256 + 128 + d0 + tx];
    __syncthreads();
    for (int i = ty; i < 32; i += 8)
      vT[(size_t)b * HD * SEQ + (size_t)(d0 + i) * SEQ + s0 + tx] = (bf16_t)tile[tx][i];
  }
}

// ---------------- flash attention (causal MQA), S^T formulation ----------------
// Q: (NTOK, DM) UNroped bf16 (RoPE + 1/sqrt(HD)*log2(e) scale applied at Q-fragment
// load — pairs (2i,2i+1) are lane-local in the fragment layout). Kb roped bf16.
// VT: (B, HD, SEQ) bf16. O: (NTOK, DM) bf16.
// One-barrier T3-minimum loop: per iter {stage(next -> buf^1); compute(buf);
// lgkmcnt(0); vmcnt(0); barrier}. WAR: the end-barrier of iter t separates all
// waves' compute-t reads of buf[cur] from any iter-t+1 stage into buf[cur].
// Visibility: vmcnt(0) (only the 8 stage loads in flight, fully hidden under
// compute) + barrier publishes the staged tile. Grid (8,16,4): block p handles
// q-tiles {15-p, p} -> uniform 34 iters.
__global__ __launch_bounds__(256, 2) void flash_attn_kernel(const bf16_t* __restrict__ Q,
                                                            const bf16_t* __restrict__ Kb,
                                                            const bf16_t* __restrict__ VT,
                                                            bf16_t* __restrict__ O) {
  __shared__ bf16_t Ks[2][64 * 128];   // row=k-token (64), 16 chunks of 8, XOR-swizzled
  __shared__ bf16_t Vs[2][64 * 128];   // row=d (128), 8 chunks of 8, XOR-swizzled
  const int tid = threadIdx.x;
  const int lane = tid & 63;
  const int wv = tid >> 6;
  const int quad = lane >> 4, l16 = lane & 15;
  const int pr = blockIdx.x, h = blockIdx.y, b = blockIdx.z;

  const bf16_t* kbase = Kb + (size_t)b * SEQ * HD;
  const bf16_t* vbase = VT + (size_t)b * HD * SEQ;

  int cur = 0;
  // prologue: stage tile 0 into buffer 0, drain, publish
#pragma unroll
  for (int i = 0; i < 4; i++) {
    int p = i * 256 + tid;
    int kr = p >> 4, kc = (p & 15) ^ (kr & 15);
    async_copy16(kbase + (size_t)kr * HD + kc * 8, &Ks[0][p * 8]);
    int vr = p >> 3, vc = (p & 7) ^ (vr & 7);
    async_copy16(vbase + (size_t)vr * SEQ + vc * 8, &Vs[0][p * 8]);
  }
  VM0;
  SB; BAR; SB;

#pragma unroll 1
  for (int ph = 0; ph < 2; ph++) {
    const int qt = ph ? pr : 15 - pr;   // block-uniform
    const int nkt = 2 * qt + 2;

    // Q fragments with fused RoPE + scale. Element j of qf[nt][ks] is
    // Q[qrow, h*128 + ks*32 + quad*8 + j]; rope pairs are (j=2jj, 2jj+1),
    // i = ks*16 + quad*4 + jj, position s = seq row.
    bf16x8 qf[2][4];
#pragma unroll
    for (int nt = 0; nt < 2; nt++) {
      const int srow = qt * 128 + wv * 32 + nt * 16 + l16;
      size_t qrow = (size_t)b * SEQ + srow;
      const bf16_t* qp = Q + qrow * DM + h * HD + quad * 8;
#pragma unroll
      for (int ks = 0; ks < 4; ks++) {
        union { uint4 u4; ushort us[8]; } u;
        u.u4 = *(const uint4*)(qp + ks * 32);
        union { ushort us[8]; bf16x8 v; } w;
#pragma unroll
        for (int jj = 0; jj < 4; jj++) {
          float x1 = __uint_as_float((uint32_t)u.us[2 * jj] << 16);
          float x2 = __uint_as_float((uint32_t)u.us[2 * jj + 1] << 16);
          int i = ks * 16 + quad * 4 + jj;
          float fr = __expf(-(float)i * ROPE_C);
          float ang = (float)srow * fr;
          float sn, cs; __sincosf(ang, &sn, &cs);
          w.us[2 * jj]     = bf16_rne((x1 * cs - x2 * sn) * ATT_SCALE);
          w.us[2 * jj + 1] = bf16_rne((x1 * sn + x2 * cs) * ATT_SCALE);
        }
        qf[nt][ks] = w.v;
      }
    }

    f32x4 oacc[8][2] = {};
    float l2[2] = {0.f, 0.f};

#pragma unroll 1
    for (int kt = 0; kt < nkt; kt++) {
      // stage next tile into buf[cur^1] (issue-first; lands during compute)
      const int has_next = !(ph == 1 && kt == nkt - 1);
      if (has_next) {
        const int k0n = (kt + 1 < nkt) ? (kt + 1) * 64 : 0;  // phase switch restarts at k=0
        bf16_t* kd = &Ks[cur ^ 1][0];
        bf16_t* vd = &Vs[cur ^ 1][0];
#pragma unroll
        for (int i = 0; i < 4; i++) {
          int p = i * 256 + tid;
          int kr = p >> 4, kc = (p & 15) ^ (kr & 15);
          async_copy16(kbase + (size_t)(k0n + kr) * HD + kc * 8, kd + p * 8);
          int vr = p >> 3, vc = (p & 7) ^ (vr & 7);
          async_copy16(vbase + (size_t)vr * SEQ + k0n + vc * 8, vd + p * 8);
        }
      }
      SB;

      const bf16_t* KsC = &Ks[cur][0];
      const bf16_t* VsC = &Vs[cur][0];

      // S^T[k][q] = K Q^T
      f32x4 sa[4][2] = {};
#pragma unroll
      for (int ks = 0; ks < 4; ks++) {
        bf16x8 ak[4];
#pragma unroll
        for (int mt = 0; mt < 4; mt++) {
          int row = mt * 16 + l16;
          int c = (ks * 4 + quad) ^ l16;
          ak[mt] = *(const bf16x8*)(KsC + (row * 16 + c) * 8);
        }
        __builtin_amdgcn_s_setprio(1);
#pragma unroll
        for (int mt = 0; mt < 4; mt++)
#pragma unroll
          for (int nt = 0; nt < 2; nt++)
            sa[mt][nt] = __builtin_amdgcn_mfma_f32_16x16x32_bf16(ak[mt], qf[nt][ks], sa[mt][nt], 0, 0, 0);
        __builtin_amdgcn_s_setprio(0);
      }

      // causal mask — only the 2 diagonal tiles (uniform branch)
      if (kt >= 2 * qt) {
        const int k0c = kt * 64;
#pragma unroll
        for (int mt = 0; mt < 4; mt++)
#pragma unroll
          for (int nt = 0; nt < 2; nt++) {
            int kg0 = k0c + mt * 16 + quad * 4;
            int qg = qt * 128 + wv * 32 + nt * 16 + l16;
#pragma unroll
            for (int r = 0; r < 4; r++)
              if (kg0 + r > qg) sa[mt][nt][r] = -INFINITY;
          }
      }

      // shift-free softmax + in-register P->bf16 B-fragment assembly
      bf16x8 bp[2][2];
#pragma unroll
      for (int nt = 0; nt < 2; nt++) {
        float rs = 0.f;
#pragma unroll
        for (int mt = 0; mt < 4; mt++)
#pragma unroll
          for (int r = 0; r < 4; r++) {
            float pv = exp2f(sa[mt][nt][r]);
            sa[mt][nt][r] = pv;
            rs += pv;
          }
        {
          float a0 = rs, a1 = rs;
          asm("v_permlane16_swap_b32 %0, %1" : "+v"(a0), "+v"(a1));
          rs = a0 + a1;
          float c0 = rs, c1 = rs;
          asm("v_permlane32_swap_b32 %0, %1" : "+v"(c0), "+v"(c1));
          rs = c0 + c1;
        }
        l2[nt] += rs;

        uint32_t d0[4], d1[4];
#pragma unroll
        for (int m = 0; m < 4; m++) {
          asm("v_cvt_pk_bf16_f32 %0, %1, %2" : "=v"(d0[m]) : "v"(sa[m][nt][0]), "v"(sa[m][nt][1]));
          asm("v_cvt_pk_bf16_f32 %0, %1, %2" : "=v"(d1[m]) : "v"(sa[m][nt][2]), "v"(sa[m][nt][3]));
        }
#pragma unroll
        for (int ks = 0; ks < 2; ks++) {
          uint32_t w0 = d0[2 * ks], w2 = d0[2 * ks + 1];
          uint32_t w1 = d1[2 * ks], w3 = d1[2 * ks + 1];
          asm("v_permlane32_swap_b32 %0, %1" : "+v"(w0), "+v"(w2));
          asm("v_permlane16_swap_b32 %0, %1" : "+v"(w0), "+v"(w2));
          asm("v_permlane32_swap_b32 %0, %1" : "+v"(w1), "+v"(w3));
          asm("v_permlane16_swap_b32 %0, %1" : "+v"(w1), "+v"(w3));
          union { uint32_t u[4]; bf16x8 v; } pk_;
          pk_.u[0] = w0; pk_.u[1] = w1; pk_.u[2] = w2; pk_.u[3] = w3;
          bp[nt][ks] = pk_.v;
        }
      }

      // O^T += V^T P^T
#pragma unroll
      for (int ks = 0; ks < 2; ks++)
#pragma unroll
        for (int dm = 0; dm < 8; dm++) {
          int row = dm * 16 + l16;
          int c = (ks * 4 + quad) ^ (row & 7);
          bf16x8 av = *(const bf16x8*)(VsC + (row * 8 + c) * 8);
          __builtin_amdgcn_s_setprio(1);
#pragma unroll
          for (int nt = 0; nt < 2; nt++)
            oacc[dm][nt] = __builtin_amdgcn_mfma_f32_16x16x32_bf16(av, bp[nt][ks], oacc[dm][nt], 0, 0, 0);
          __builtin_amdgcn_s_setprio(0);
        }

      // end-of-iter: all LDS reads done, staged tile landed, publish
      LGKM0;
      VM0;
      SB; BAR; SB;
      cur ^= 1;
    }

    float inv[2];
#pragma unroll
    for (int nt = 0; nt < 2; nt++) inv[nt] = 1.f / l2[nt];
#pragma unroll
    for (int dm = 0; dm < 8; dm++)
#pragma unroll
      for (int nt = 0; nt < 2; nt++) {
        size_t row = (size_t)b * SEQ + qt * 128 + wv * 32 + nt * 16 + l16;
        size_t col = (size_t)h * HD + dm * 16 + quad * 4;
        union { ushort4 u; bf16_t bb[4]; } pk;
#pragma unroll
        for (int r = 0; r < 4; r++) pk.bb[r] = (bf16_t)(oacc[dm][nt][r] * inv[nt]);
        *(ushort4*)(O + row * DM + col) = pk.u;
      }
  }
}

// ---------------- launch ----------------

extern "C" void kernel_launch(void* const* d_in, const int* in_sizes, int n_in,
                              void* d_out, int out_size, void* d_ws, size_t ws_size,
                              hipStream_t stream) {
  const float* x  = (const float*)d_in[0];
  const float* wq = (const float*)d_in[1];
  const float* bq = (const float*)d_in[2];
  const float* wk = (const float*)d_in[3];
  const float* bk = (const float*)d_in[4];
  const float* wv = (const float*)d_in[5];
  const float* bv = (const float*)d_in[6];
  const float* wo = (const float*)d_in[7];
  const float* bo = (const float*)d_in[8];
  char* ws = (char*)d_ws;

  bf16_t* xbf  = (bf16_t*)(ws);                 // 33.5 MB  (reused as attn later)
  bf16_t* qbf  = (bf16_t*)(ws + 33554432ull);   // 33.5 MB
  bf16_t* wqT  = (bf16_t*)(ws + 67108864ull);   // 8.4 MB
  bf16_t* woT  = (bf16_t*)(ws + 75497472ull);   // 8.4 MB
  bf16_t* wkvT = (bf16_t*)(ws + 83886080ull);   // 1 MB
  float*  kvf  = (float* )(ws + 84934656ull);   // 8.4 MB
  bf16_t* kbf  = (bf16_t*)(ws + 93323264ull);   // 2 MB
  bf16_t* vT   = (bf16_t*)(ws + 95420416ull);   // 2 MB
  bf16_t* attn = xbf;  // alias: x_bf16 dead after the two input GEMMs

  float* out = (float*)d_out;
  float* kh  = out + 16777216ull;
  float* vh  = kh + 1048576ull;

  hipFuncSetAttribute((const void*)gemm256<bf16_t>, hipFuncAttributeMaxDynamicSharedMemorySize, 131072);
  hipFuncSetAttribute((const void*)gemm256<float>,  hipFuncAttributeMaxDynamicSharedMemorySize, 131072);

  convert_x_bf16<<<16384, 256, 0, stream>>>(x, xbf, 4194304);
  transpose_qo<<<dim3(64, 64, 2), 256, 0, stream>>>(wq, wo, wqT, woT);
  transpose_wkv<<<dim3(4, 64, 2), 256, 0, stream>>>(wk, wv, wkvT);

  gemm256<bf16_t><<<256, 512, 131072, stream>>>(xbf, wqT, bq, qbf, 8192, 2048, 2048);
  gemm_bt_kv<<<dim3(64, 2), 256, 0, stream>>>(xbf, wkvT, bk, bv, kvf, 8192, 256, 2048);

  rope_kv_tv<<<3072, 256, 0, stream>>>(kvf, kh, vh, kbf, vT);

  flash_attn_kernel<<<dim3(8, 16, 4), 256, 0, stream>>>(qbf, kbf, vT, attn);

  gemm256<float><<<256, 512, 131072, stream>>>(attn, woT, bo, out, 8192, 2048, 2048);
}

// Round 6
// 462.129 us; speedup vs baseline: 1.3675x; 1.0030x over previous
//
#include <hip/hip_runtime.h>
#include <hip/hip_bf16.h>
#include <cstdint>
#include <cstddef>

#define SEQ 2048
#define DM 2048
#define NHEADS 16
#define HD 128
#define NTOK 8192   // 4*2048
#define BATCH 4

typedef __bf16 bf16_t;
typedef bf16_t bf16x8 __attribute__((ext_vector_type(8)));
typedef float f32x4 __attribute__((ext_vector_type(4)));

__device__ __forceinline__ void async_copy16(const bf16_t* g, bf16_t* l) {
  __builtin_amdgcn_global_load_lds(
      (const __attribute__((address_space(1))) unsigned int*)g,
      (__attribute__((address_space(3))) unsigned int*)l, 16, 0, 0);
}

__device__ __forceinline__ void store_out(float* p, float v)  { *p = v; }
__device__ __forceinline__ void store_out(bf16_t* p, float v) { *p = (bf16_t)v; }

__device__ __forceinline__ ushort bf16_rne(float f) {
  union { float f; uint32_t u; } t; t.f = f;
  return (ushort)((t.u + 0x7fff + ((t.u >> 16) & 1)) >> 16);
}

#define SB  __builtin_amdgcn_sched_barrier(0)
#define BAR __builtin_amdgcn_s_barrier()
#define LGKM0 asm volatile("s_waitcnt lgkmcnt(0)" ::: "memory")
#define VM0 asm volatile("s_waitcnt vmcnt(0)" ::: "memory")

// ---------------- fused preprocessing ----------------
// blocks [0, 16384):        convert x f32 -> bf16 (float4/ushort4, exact grid)
// blocks [16384, 24576):    transpose wq / wo (2048x2048) -> bf16
// blocks [24576, 25088):    transpose wk / wv (2048x128) -> wkvT (256x2048)
__global__ void preprocess(const float* __restrict__ x, bf16_t* __restrict__ xbf,
                           const float* __restrict__ wq, const float* __restrict__ wo,
                           bf16_t* __restrict__ wqT, bf16_t* __restrict__ woT,
                           const float* __restrict__ wk, const float* __restrict__ wv,
                           bf16_t* __restrict__ wkvT) {
  __shared__ float tile[32][33];
  int bid = blockIdx.x;
  if (bid < 16384) {
    int i = bid * 256 + threadIdx.x;   // 16384*256 == 4194304 exactly
    float4 v = ((const float4*)x)[i];
    union { ushort4 u; bf16_t b[4]; } o;
    o.b[0] = (bf16_t)v.x; o.b[1] = (bf16_t)v.y; o.b[2] = (bf16_t)v.z; o.b[3] = (bf16_t)v.w;
    *(ushort4*)(xbf + (size_t)i * 4) = o.u;
  } else if (bid < 16384 + 8192) {
    int t = bid - 16384;               // 64 x 64 x 2
    const float* in = (t >> 12) ? wo : wq;
    bf16_t* out = (t >> 12) ? woT : wqT;
    int c0 = (t & 63) * 32, r0 = ((t >> 6) & 63) * 32;
    int tx = threadIdx.x & 31, ty = threadIdx.x >> 5;
    for (int i = ty; i < 32; i += 8) tile[i][tx] = in[(size_t)(r0 + i) * 2048 + c0 + tx];
    __syncthreads();
    for (int i = ty; i < 32; i += 8) out[(size_t)(c0 + i) * 2048 + r0 + tx] = (bf16_t)tile[tx][i];
  } else {
    int t = bid - 16384 - 8192;        // 4 x 64 x 2
    const float* in = (t >> 8) ? wv : wk;
    bf16_t* out = wkvT + (size_t)(t >> 8) * 128 * 2048;
    int c0 = (t & 3) * 32, r0 = ((t >> 2) & 63) * 32;
    int tx = threadIdx.x & 31, ty = threadIdx.x >> 5;
    for (int i = ty; i < 32; i += 8) tile[i][tx] = in[(size_t)(r0 + i) * 128 + c0 + tx];
    __syncthreads();
    for (int i = ty; i < 32; i += 8) out[(size_t)(c0 + i) * 2048 + r0 + tx] = (bf16_t)tile[tx][i];
  }
}

// ---------------- m97-style GEMM (KV projection), dual bias ----------------
__global__ __launch_bounds__(256) void gemm_bt_kv(const bf16_t* __restrict__ A,
                                                  const bf16_t* __restrict__ Bt,
                                                  const float* __restrict__ bk,
                                                  const float* __restrict__ bv,
                                                  float* __restrict__ C, int M, int N, int K) {
  __shared__ bf16_t As[128 * 32];
  __shared__ bf16_t Bs[128 * 32];
  const int tid = threadIdx.x;
  const int lane = tid & 63;
  const int wv = tid >> 6;
  const int wi = wv >> 1, wj = wv & 1;
  const int quad = lane >> 4, l16 = lane & 15;
  const size_t m0 = (size_t)blockIdx.x * 128, n0 = (size_t)blockIdx.y * 128;

  f32x4 acc[4][4] = {};

  const bf16_t* ag = A + (m0 + (tid >> 2)) * K + (tid & 3) * 8;
  const bf16_t* bg = Bt + (n0 + (tid >> 2)) * K + (tid & 3) * 8;
  bf16_t* asd = As + tid * 8;
  bf16_t* bsd = Bs + tid * 8;
  const int nk = K >> 5;
  for (int kt = 0; kt < nk; kt++) {
    async_copy16(ag, asd);
    async_copy16(ag + (size_t)64 * K, asd + 64 * 32);
    async_copy16(bg, bsd);
    async_copy16(bg + (size_t)64 * K, bsd + 64 * 32);
    ag += 32; bg += 32;
    __syncthreads();
    bf16x8 af[4], bf[4];
#pragma unroll
    for (int mt = 0; mt < 4; mt++)
      af[mt] = *(const bf16x8*)(As + (wi * 64 + mt * 16 + l16) * 32 + quad * 8);
#pragma unroll
    for (int nt = 0; nt < 4; nt++)
      bf[nt] = *(const bf16x8*)(Bs + (wj * 64 + nt * 16 + l16) * 32 + quad * 8);
#pragma unroll
    for (int mt = 0; mt < 4; mt++)
#pragma unroll
      for (int nt = 0; nt < 4; nt++)
        acc[mt][nt] = __builtin_amdgcn_mfma_f32_16x16x32_bf16(af[mt], bf[nt], acc[mt][nt], 0, 0, 0);
    __syncthreads();
  }
#pragma unroll
  for (int nt = 0; nt < 4; nt++) {
    size_t col = n0 + wj * 64 + nt * 16 + l16;
    float bb = (col < 128) ? bk[col] : bv[col - 128];
#pragma unroll
    for (int mt = 0; mt < 4; mt++) {
      size_t row = m0 + wi * 64 + mt * 16 + quad * 4;
#pragma unroll
      for (int r = 0; r < 4; r++) C[(row + r) * N + col] = acc[mt][nt][r] + bb;
    }
  }
}

// ---------------- 256x256 8-phase GEMM: C = A @ Bt^T + bias ----------------
// (verified round-3 kernel, unchanged)
template <typename OutT>
__global__ __launch_bounds__(512, 2) void gemm256(const bf16_t* __restrict__ A,
                                                  const bf16_t* __restrict__ Bt,
                                                  const float* __restrict__ bias,
                                                  OutT* __restrict__ C, int M, int N, int K) {
  extern __shared__ char smem_raw[];
  bf16_t* As_ = (bf16_t*)smem_raw;          // 2 slots x 2 kh x 8192 el = 64 KiB
  bf16_t* Bs_ = As_ + 32768;                // same, 64 KiB

  const int tid = threadIdx.x;
  const int lane = tid & 63;
  const int wv = tid >> 6;
  const int wr = wv >> 2, wc = wv & 3;
  const int quad = lane >> 4, l16 = lane & 15;

  const int bid = blockIdx.x;
  const int g = (bid & 7) * 32 + (bid >> 3);
  const size_t m0 = (size_t)(g >> 3) * 256;
  const size_t n0 = (size_t)(g & 7) * 256;

  auto mkrow = [](int s) { int rp = s >> 3; int Cc = (s & 7) ^ (rp & 7); return rp * 2 + (Cc >> 2); };
  auto mkkc  = [](int s) { int rp = s >> 3; int Cc = (s & 7) ^ (rp & 7); return (Cc & 3) * 8; };
  const bf16_t* pA0 = A  + (size_t)(m0 + mkrow(tid)) * K + mkkc(tid);
  const bf16_t* pA1 = A  + (size_t)(m0 + mkrow(tid + 512)) * K + mkkc(tid + 512);
  const bf16_t* pB0 = Bt + (size_t)(n0 + mkrow(tid)) * K + mkkc(tid);
  const bf16_t* pB1 = Bt + (size_t)(n0 + mkrow(tid + 512)) * K + mkkc(tid + 512);

#define STAGE_A(SLOT, KH, KT) do { \
    async_copy16(pA0 + (size_t)(KT) * 64 + (KH) * 32, As_ + (SLOT) * 16384 + (KH) * 8192 + tid * 8); \
    async_copy16(pA1 + (size_t)(KT) * 64 + (KH) * 32, As_ + (SLOT) * 16384 + (KH) * 8192 + (tid + 512) * 8); \
  } while (0)
#define STAGE_B(SLOT, KH, KT) do { \
    async_copy16(pB0 + (size_t)(KT) * 64 + (KH) * 32, Bs_ + (SLOT) * 16384 + (KH) * 8192 + tid * 8); \
    async_copy16(pB1 + (size_t)(KT) * 64 + (KH) * 32, Bs_ + (SLOT) * 16384 + (KH) * 8192 + (tid + 512) * 8); \
  } while (0)

  int aoffs[8], boffs[4];
#pragma unroll
  for (int mi = 0; mi < 8; mi++) {
    int row = wr * 128 + mi * 16 + l16;
    int rp = row >> 1, Cc = (row & 1) * 4 + quad;
    aoffs[mi] = rp * 64 + (Cc ^ (rp & 7)) * 8;
  }
#pragma unroll
  for (int ni = 0; ni < 4; ni++) {
    int row = wc * 64 + ni * 16 + l16;
    int rp = row >> 1, Cc = (row & 1) * 4 + quad;
    boffs[ni] = rp * 64 + (Cc ^ (rp & 7)) * 8;
  }

  f32x4 acc[8][4] = {};
  bf16x8 afr[8], b0, b1;

#define LOAD_A(SLOT, KS) do { _Pragma("unroll") \
    for (int mi = 0; mi < 8; mi++) afr[mi] = *(const bf16x8*)(As_ + (SLOT) * 16384 + (KS) * 8192 + aoffs[mi]); \
  } while (0)
#define LOAD_B2(SLOT, KS, NF0) do { \
    b0 = *(const bf16x8*)(Bs_ + (SLOT) * 16384 + (KS) * 8192 + boffs[NF0]); \
    b1 = *(const bf16x8*)(Bs_ + (SLOT) * 16384 + (KS) * 8192 + boffs[(NF0) + 1]); \
  } while (0)
#define MFMA16(NF0) do { __builtin_amdgcn_s_setprio(1); _Pragma("unroll") \
    for (int mi = 0; mi < 8; mi++) { \
      acc[mi][NF0] = __builtin_amdgcn_mfma_f32_16x16x32_bf16(afr[mi], b0, acc[mi][NF0], 0, 0, 0); \
      acc[mi][(NF0) + 1] = __builtin_amdgcn_mfma_f32_16x16x32_bf16(afr[mi], b1, acc[mi][(NF0) + 1], 0, 0, 0); \
    } __builtin_amdgcn_s_setprio(0); } while (0)

  const int NI = K >> 7;

  STAGE_A(0, 0, 0); STAGE_B(0, 0, 0);
  STAGE_A(0, 1, 0); STAGE_B(0, 1, 0);
  STAGE_A(1, 0, 1); STAGE_B(1, 0, 1);
  VM0;
  SB; BAR; SB;

#pragma unroll 1
  for (int j = 0; j < NI; j++) {
    const int last = (j == NI - 1);
    LOAD_A(0, 0); LOAD_B2(0, 0, 0);
    STAGE_A(1, 1, 2 * j + 1);
    SB; BAR; LGKM0; SB; MFMA16(0); SB; BAR;
    LOAD_B2(0, 0, 2);
    STAGE_B(1, 1, 2 * j + 1);
    SB; BAR; LGKM0; SB; MFMA16(2); SB; BAR;
    LOAD_A(0, 1); LOAD_B2(0, 1, 0);
    if (!last) STAGE_A(0, 0, 2 * j + 2);
    SB; BAR; LGKM0; SB; MFMA16(0); SB; BAR;
    LOAD_B2(0, 1, 2);
    if (!last) STAGE_B(0, 0, 2 * j + 2);
    SB;
    if (!last) { asm volatile("s_waitcnt vmcnt(4)" ::: "memory"); }
    else       { VM0; }
    BAR; LGKM0; SB; MFMA16(2); SB; BAR;
    LOAD_A(1, 0); LOAD_B2(1, 0, 0);
    if (!last) STAGE_A(0, 1, 2 * j + 2);
    SB; BAR; LGKM0; SB; MFMA16(0); SB; BAR;
    LOAD_B2(1, 0, 2);
    if (!last) STAGE_B(0, 1, 2 * j + 2);
    SB; BAR; LGKM0; SB; MFMA16(2); SB; BAR;
    LOAD_A(1, 1); LOAD_B2(1, 1, 0);
    if (!last) STAGE_A(1, 0, 2 * j + 3);
    SB; BAR; LGKM0; SB; MFMA16(0); SB; BAR;
    LOAD_B2(1, 1, 2);
    if (!last) STAGE_B(1, 0, 2 * j + 3);
    SB;
    if (!last) { asm volatile("s_waitcnt vmcnt(4)" ::: "memory"); }
    else       { VM0; }
    BAR; LGKM0; SB; MFMA16(2); SB; BAR;
  }

#pragma unroll
  for (int ni = 0; ni < 4; ni++) {
    size_t col = n0 + wc * 64 + ni * 16 + l16;
    float bb = bias[col];
#pragma unroll
    for (int mi = 0; mi < 8; mi++) {
      size_t row = m0 + wr * 128 + mi * 16 + quad * 4;
#pragma unroll
      for (int r = 0; r < 4; r++) store_out(&C[(row + r) * N + col], acc[mi][ni][r] + bb);
    }
  }
#undef STAGE_A
#undef STAGE_B
#undef LOAD_A
#undef LOAD_B2
#undef MFMA16
}

// ---------------- RoPE ----------------
// freq_i = 10000^(-2i/128) = exp(-i * ln(10000)/64)
#define ROPE_C 0.14391156831212787f
// attention scale folded into Q: 1/sqrt(128) * log2(e)  (softmax via exp2)
#define ATT_SCALE 0.1275174462517703f

// fused: rope K half of kvf -> kh/kbf, copy V half -> vh  (blocks 0..2047)
//        transpose V half -> vT                            (blocks 2048..3071)
__global__ void rope_kv_tv(const float* __restrict__ kvf, float* __restrict__ kh,
                           float* __restrict__ vh, bf16_t* __restrict__ kbf,
                           bf16_t* __restrict__ vT) {
  int bid = blockIdx.x;
  if (bid < 2048) {
    int idx = bid * 256 + threadIdx.x;  // one per K-pair
    int t = idx >> 6;
    int i = idx & 63;
    int s = t & (SEQ - 1);
    const float* base = kvf + (size_t)t * 256;
    float x1 = base[2 * i], x2 = base[2 * i + 1];
    float fr = __expf(-(float)i * ROPE_C);
    float ang = (float)s * fr;
    float sn, cs; __sincosf(ang, &sn, &cs);
    float k1 = x1 * cs - x2 * sn, k2 = x1 * sn + x2 * cs;
    size_t o = (size_t)t * HD + 2 * i;
    kh[o] = k1; kh[o + 1] = k2;
    kbf[o] = (bf16_t)k1; kbf[o + 1] = (bf16_t)k2;
    vh[o] = base[128 + 2 * i];
    vh[o + 1] = base[128 + 2 * i + 1];
  } else {
    __shared__ float tile[32][33];
    int t = bid - 2048;                 // 64 x 4 x 4
    int s0 = (t & 63) * 32, d0 = ((t >> 6) & 3) * 32, b = t >> 8;
    int tx = threadIdx.x & 31, ty = threadIdx.x >> 5;
    for (int i = ty; i < 32; i += 8)
      tile[i][tx] = kvf[(size_t)(b * SEQ + s0 + i) * 256 + 128 + d0 + tx];
    __syncthreads();
    for (int i = ty; i < 32; i += 8)
      vT[(size_t)b * HD * SEQ + (size_t)(d0 + i) * SEQ + s0 + tx] = (bf16_t)tile[tx][i];
  }
}

// ---------------- flash attention (causal MQA), S^T formulation ----------------
// (round-4 verified kernel, verbatim: 124 us, passed)
__global__ __launch_bounds__(256, 2) void flash_attn_kernel(const bf16_t* __restrict__ Q,
                                                            const bf16_t* __restrict__ Kb,
                                                            const bf16_t* __restrict__ VT,
                                                            bf16_t* __restrict__ O) {
  __shared__ bf16_t Ks[2][64 * 128];   // row=k-token (64), 16 chunks of 8, XOR-swizzled
  __shared__ bf16_t Vs[2][64 * 128];   // row=d (128), 8 chunks of 8, XOR-swizzled
  const int tid = threadIdx.x;
  const int lane = tid & 63;
  const int wv = tid >> 6;
  const int quad = lane >> 4, l16 = lane & 15;
  const int pr = blockIdx.x, h = blockIdx.y, b = blockIdx.z;

  const bf16_t* kbase = Kb + (size_t)b * SEQ * HD;
  const bf16_t* vbase = VT + (size_t)b * HD * SEQ;

  int cur = 0;
  // prologue: stage tile 0 into buffer 0, drain, publish
#pragma unroll
  for (int i = 0; i < 4; i++) {
    int p = i * 256 + tid;
    int kr = p >> 4, kc = (p & 15) ^ (kr & 15);
    async_copy16(kbase + (size_t)kr * HD + kc * 8, &Ks[0][p * 8]);
    int vr = p >> 3, vc = (p & 7) ^ (vr & 7);
    async_copy16(vbase + (size_t)vr * SEQ + vc * 8, &Vs[0][p * 8]);
  }
  VM0;
  SB; BAR; SB;

#pragma unroll 1
  for (int ph = 0; ph < 2; ph++) {
    const int qt = ph ? pr : 15 - pr;   // block-uniform
    const int nkt = 2 * qt + 2;

    // Q fragments with fused RoPE + scale. Element j of qf[nt][ks] is
    // Q[qrow, h*128 + ks*32 + quad*8 + j]; rope pairs are (j=2jj, 2jj+1),
    // i = ks*16 + quad*4 + jj, position s = seq row.
    bf16x8 qf[2][4];
#pragma unroll
    for (int nt = 0; nt < 2; nt++) {
      const int srow = qt * 128 + wv * 32 + nt * 16 + l16;
      size_t qrow = (size_t)b * SEQ + srow;
      const bf16_t* qp = Q + qrow * DM + h * HD + quad * 8;
#pragma unroll
      for (int ks = 0; ks < 4; ks++) {
        union { uint4 u4; ushort us[8]; } u;
        u.u4 = *(const uint4*)(qp + ks * 32);
        union { ushort us[8]; bf16x8 v; } w;
#pragma unroll
        for (int jj = 0; jj < 4; jj++) {
          float x1 = __uint_as_float((uint32_t)u.us[2 * jj] << 16);
          float x2 = __uint_as_float((uint32_t)u.us[2 * jj + 1] << 16);
          int i = ks * 16 + quad * 4 + jj;
          float fr = __expf(-(float)i * ROPE_C);
          float ang = (float)srow * fr;
          float sn, cs; __sincosf(ang, &sn, &cs);
          w.us[2 * jj]     = bf16_rne((x1 * cs - x2 * sn) * ATT_SCALE);
          w.us[2 * jj + 1] = bf16_rne((x1 * sn + x2 * cs) * ATT_SCALE);
        }
        qf[nt][ks] = w.v;
      }
    }

    f32x4 oacc[8][2] = {};
    float l2[2] = {0.f, 0.f};

#pragma unroll 1
    for (int kt = 0; kt < nkt; kt++) {
      // stage next tile into buf[cur^1] (issue-first; lands during compute)
      const int has_next = !(ph == 1 && kt == nkt - 1);
      if (has_next) {
        const int k0n = (kt + 1 < nkt) ? (kt + 1) * 64 : 0;  // phase switch restarts at k=0
        bf16_t* kd = &Ks[cur ^ 1][0];
        bf16_t* vd = &Vs[cur ^ 1][0];
#pragma unroll
        for (int i = 0; i < 4; i++) {
          int p = i * 256 + tid;
          int kr = p >> 4, kc = (p & 15) ^ (kr & 15);
          async_copy16(kbase + (size_t)(k0n + kr) * HD + kc * 8, kd + p * 8);
          int vr = p >> 3, vc = (p & 7) ^ (vr & 7);
          async_copy16(vbase + (size_t)vr * SEQ + k0n + vc * 8, vd + p * 8);
        }
      }
      SB;

      const bf16_t* KsC = &Ks[cur][0];
      const bf16_t* VsC = &Vs[cur][0];

      // S^T[k][q] = K Q^T
      f32x4 sa[4][2] = {};
#pragma unroll
      for (int ks = 0; ks < 4; ks++) {
        bf16x8 ak[4];
#pragma unroll
        for (int mt = 0; mt < 4; mt++) {
          int row = mt * 16 + l16;
          int c = (ks * 4 + quad) ^ l16;
          ak[mt] = *(const bf16x8*)(KsC + (row * 16 + c) * 8);
        }
        __builtin_amdgcn_s_setprio(1);
#pragma unroll
        for (int mt = 0; mt < 4; mt++)
#pragma unroll
          for (int nt = 0; nt < 2; nt++)
            sa[mt][nt] = __builtin_amdgcn_mfma_f32_16x16x32_bf16(ak[mt], qf[nt][ks], sa[mt][nt], 0, 0, 0);
        __builtin_amdgcn_s_setprio(0);
      }

      // causal mask — only the 2 diagonal tiles (uniform branch)
      if (kt >= 2 * qt) {
        const int k0c = kt * 64;
#pragma unroll
        for (int mt = 0; mt < 4; mt++)
#pragma unroll
          for (int nt = 0; nt < 2; nt++) {
            int kg0 = k0c + mt * 16 + quad * 4;
            int qg = qt * 128 + wv * 32 + nt * 16 + l16;
#pragma unroll
            for (int r = 0; r < 4; r++)
              if (kg0 + r > qg) sa[mt][nt][r] = -INFINITY;
          }
      }

      // shift-free softmax + in-register P->bf16 B-fragment assembly
      bf16x8 bp[2][2];
#pragma unroll
      for (int nt = 0; nt < 2; nt++) {
        float rs = 0.f;
#pragma unroll
        for (int mt = 0; mt < 4; mt++)
#pragma unroll
          for (int r = 0; r < 4; r++) {
            float pv = exp2f(sa[mt][nt][r]);
            sa[mt][nt][r] = pv;
            rs += pv;
          }
        {
          float a0 = rs, a1 = rs;
          asm("v_permlane16_swap_b32 %0, %1" : "+v"(a0), "+v"(a1));
          rs = a0 + a1;
          float c0 = rs, c1 = rs;
          asm("v_permlane32_swap_b32 %0, %1" : "+v"(c0), "+v"(c1));
          rs = c0 + c1;
        }
        l2[nt] += rs;

        uint32_t d0[4], d1[4];
#pragma unroll
        for (int m = 0; m < 4; m++) {
          asm("v_cvt_pk_bf16_f32 %0, %1, %2" : "=v"(d0[m]) : "v"(sa[m][nt][0]), "v"(sa[m][nt][1]));
          asm("v_cvt_pk_bf16_f32 %0, %1, %2" : "=v"(d1[m]) : "v"(sa[m][nt][2]), "v"(sa[m][nt][3]));
        }
#pragma unroll
        for (int ks = 0; ks < 2; ks++) {
          uint32_t w0 = d0[2 * ks], w2 = d0[2 * ks + 1];
          uint32_t w1 = d1[2 * ks], w3 = d1[2 * ks + 1];
          asm("v_permlane32_swap_b32 %0, %1" : "+v"(w0), "+v"(w2));
          asm("v_permlane16_swap_b32 %0, %1" : "+v"(w0), "+v"(w2));
          asm("v_permlane32_swap_b32 %0, %1" : "+v"(w1), "+v"(w3));
          asm("v_permlane16_swap_b32 %0, %1" : "+v"(w1), "+v"(w3));
          union { uint32_t u[4]; bf16x8 v; } pk_;
          pk_.u[0] = w0; pk_.u[1] = w1; pk_.u[2] = w2; pk_.u[3] = w3;
          bp[nt][ks] = pk_.v;
        }
      }

      // O^T += V^T P^T
#pragma unroll
      for (int ks = 0; ks < 2; ks++)
#pragma unroll
        for (int dm = 0; dm < 8; dm++) {
          int row = dm * 16 + l16;
          int c = (ks * 4 + quad) ^ (row & 7);
          bf16x8 av = *(const bf16x8*)(VsC + (row * 8 + c) * 8);
          __builtin_amdgcn_s_setprio(1);
#pragma unroll
          for (int nt = 0; nt < 2; nt++)
            oacc[dm][nt] = __builtin_amdgcn_mfma_f32_16x16x32_bf16(av, bp[nt][ks], oacc[dm][nt], 0, 0, 0);
          __builtin_amdgcn_s_setprio(0);
        }

      // end-of-iter: all LDS reads done, staged tile landed, publish
      LGKM0;
      VM0;
      SB; BAR; SB;
      cur ^= 1;
    }

    float inv[2];
#pragma unroll
    for (int nt = 0; nt < 2; nt++) inv[nt] = 1.f / l2[nt];
#pragma unroll
    for (int dm = 0; dm < 8; dm++)
#pragma unroll
      for (int nt = 0; nt < 2; nt++) {
        size_t row = (size_t)b * SEQ + qt * 128 + wv * 32 + nt * 16 + l16;
        size_t col = (size_t)h * HD + dm * 16 + quad * 4;
        union { ushort4 u; bf16_t bb[4]; } pk;
#pragma unroll
        for (int r = 0; r < 4; r++) pk.bb[r] = (bf16_t)(oacc[dm][nt][r] * inv[nt]);
        *(ushort4*)(O + row * DM + col) = pk.u;
      }
  }
}

// ---------------- launch ----------------

extern "C" void kernel_launch(void* const* d_in, const int* in_sizes, int n_in,
                              void* d_out, int out_size, void* d_ws, size_t ws_size,
                              hipStream_t stream) {
  const float* x  = (const float*)d_in[0];
  const float* wq = (const float*)d_in[1];
  const float* bq = (const float*)d_in[2];
  const float* wk = (const float*)d_in[3];
  const float* bk = (const float*)d_in[4];
  const float* wv = (const float*)d_in[5];
  const float* bv = (const float*)d_in[6];
  const float* wo = (const float*)d_in[7];
  const float* bo = (const float*)d_in[8];
  char* ws = (char*)d_ws;

  bf16_t* xbf  = (bf16_t*)(ws);                 // 33.5 MB  (reused as attn later)
  bf16_t* qbf  = (bf16_t*)(ws + 33554432ull);   // 33.5 MB
  bf16_t* wqT  = (bf16_t*)(ws + 67108864ull);   // 8.4 MB
  bf16_t* woT  = (bf16_t*)(ws + 75497472ull);   // 8.4 MB
  bf16_t* wkvT = (bf16_t*)(ws + 83886080ull);   // 1 MB
  float*  kvf  = (float* )(ws + 84934656ull);   // 8.4 MB
  bf16_t* kbf  = (bf16_t*)(ws + 93323264ull);   // 2 MB
  bf16_t* vT   = (bf16_t*)(ws + 95420416ull);   // 2 MB
  bf16_t* attn = xbf;  // alias: x_bf16 dead after the two input GEMMs

  float* out = (float*)d_out;
  float* kh  = out + 16777216ull;
  float* vh  = kh + 1048576ull;

  hipFuncSetAttribute((const void*)gemm256<bf16_t>, hipFuncAttributeMaxDynamicSharedMemorySize, 131072);
  hipFuncSetAttribute((const void*)gemm256<float>,  hipFuncAttributeMaxDynamicSharedMemorySize, 131072);

  preprocess<<<25088, 256, 0, stream>>>(x, xbf, wq, wo, wqT, woT, wk, wv, wkvT);

  gemm256<bf16_t><<<256, 512, 131072, stream>>>(xbf, wqT, bq, qbf, 8192, 2048, 2048);
  gemm_bt_kv<<<dim3(64, 2), 256, 0, stream>>>(xbf, wkvT, bk, bv, kvf, 8192, 256, 2048);

  rope_kv_tv<<<3072, 256, 0, stream>>>(kvf, kh, vh, kbf, vT);

  flash_attn_kernel<<<dim3(8, 16, 4), 256, 0, stream>>>(qbf, kbf, vT, attn);

  gemm256<float><<<256, 512, 131072, stream>>>(attn, woT, bo, out, 8192, 2048, 2048);
}

// Round 9
// 448.609 us; speedup vs baseline: 1.4087x; 1.0301x over previous
//
#include <hip/hip_runtime.h>
#include <hip/hip_bf16.h>
#include <cstdint>
#include <cstddef>

#define SEQ 2048
#define DM 2048
#define NHEADS 16
#define HD 128
#define NTOK 8192   // 4*2048
#define BATCH 4

typedef __bf16 bf16_t;
typedef bf16_t bf16x8 __attribute__((ext_vector_type(8)));
typedef float f32x4 __attribute__((ext_vector_type(4)));

__device__ __forceinline__ void async_copy16(const bf16_t* g, bf16_t* l) {
  __builtin_amdgcn_global_load_lds(
      (const __attribute__((address_space(1))) unsigned int*)g,
      (__attribute__((address_space(3))) unsigned int*)l, 16, 0, 0);
}

__device__ __forceinline__ void store_out(float* p, float v)  { *p = v; }
__device__ __forceinline__ void store_out(bf16_t* p, float v) { *p = (bf16_t)v; }

__device__ __forceinline__ ushort bf16_rne(float f) {
  union { float f; uint32_t u; } t; t.f = f;
  return (ushort)((t.u + 0x7fff + ((t.u >> 16) & 1)) >> 16);
}

#define SB  __builtin_amdgcn_sched_barrier(0)
#define BAR __builtin_amdgcn_s_barrier()
#define LGKM0 asm volatile("s_waitcnt lgkmcnt(0)" ::: "memory")
#define VM0 asm volatile("s_waitcnt vmcnt(0)" ::: "memory")

// ---------------- fused preprocessing (verified round-6) ----------------
__global__ void preprocess(const float* __restrict__ x, bf16_t* __restrict__ xbf,
                           const float* __restrict__ wq, const float* __restrict__ wo,
                           bf16_t* __restrict__ wqT, bf16_t* __restrict__ woT,
                           const float* __restrict__ wk, const float* __restrict__ wv,
                           bf16_t* __restrict__ wkvT) {
  __shared__ float tile[32][33];
  int bid = blockIdx.x;
  if (bid < 16384) {
    int i = bid * 256 + threadIdx.x;   // 16384*256 == 4194304 exactly
    float4 v = ((const float4*)x)[i];
    union { ushort4 u; bf16_t b[4]; } o;
    o.b[0] = (bf16_t)v.x; o.b[1] = (bf16_t)v.y; o.b[2] = (bf16_t)v.z; o.b[3] = (bf16_t)v.w;
    *(ushort4*)(xbf + (size_t)i * 4) = o.u;
  } else if (bid < 16384 + 8192) {
    int t = bid - 16384;               // 64 x 64 x 2
    const float* in = (t >> 12) ? wo : wq;
    bf16_t* out = (t >> 12) ? woT : wqT;
    int c0 = (t & 63) * 32, r0 = ((t >> 6) & 63) * 32;
    int tx = threadIdx.x & 31, ty = threadIdx.x >> 5;
    for (int i = ty; i < 32; i += 8) tile[i][tx] = in[(size_t)(r0 + i) * 2048 + c0 + tx];
    __syncthreads();
    for (int i = ty; i < 32; i += 8) out[(size_t)(c0 + i) * 2048 + r0 + tx] = (bf16_t)tile[tx][i];
  } else {
    int t = bid - 16384 - 8192;        // 4 x 64 x 2
    const float* in = (t >> 8) ? wv : wk;
    bf16_t* out = wkvT + (size_t)(t >> 8) * 128 * 2048;
    int c0 = (t & 3) * 32, r0 = ((t >> 2) & 63) * 32;
    int tx = threadIdx.x & 31, ty = threadIdx.x >> 5;
    for (int i = ty; i < 32; i += 8) tile[i][tx] = in[(size_t)(r0 + i) * 128 + c0 + tx];
    __syncthreads();
    for (int i = ty; i < 32; i += 8) out[(size_t)(c0 + i) * 2048 + r0 + tx] = (bf16_t)tile[tx][i];
  }
}

// ---------------- KV projection, split-K partials (no bias; summed in rope_kv_tv) ----------------
// grid (64, 2, 2): z = K-half. Partial z into Cz. 256 blocks (full machine),
// 32 serial K-iterations per block instead of 64. Deterministic (no atomics).
__global__ __launch_bounds__(256) void gemm_kv_split(const bf16_t* __restrict__ A,
                                                     const bf16_t* __restrict__ Bt,
                                                     float* __restrict__ C0,
                                                     float* __restrict__ C1,
                                                     int M, int N, int K, int KD) {
  __shared__ bf16_t As[128 * 32];
  __shared__ bf16_t Bs[128 * 32];
  const int tid = threadIdx.x;
  const int lane = tid & 63;
  const int wv = tid >> 6;
  const int wi = wv >> 1, wj = wv & 1;
  const int quad = lane >> 4, l16 = lane & 15;
  const size_t m0 = (size_t)blockIdx.x * 128, n0 = (size_t)blockIdx.y * 128;
  const int z = blockIdx.z;

  f32x4 acc[4][4] = {};

  const bf16_t* ag = A + (m0 + (tid >> 2)) * K + (size_t)z * KD + (tid & 3) * 8;
  const bf16_t* bg = Bt + (n0 + (tid >> 2)) * K + (size_t)z * KD + (tid & 3) * 8;
  bf16_t* asd = As + tid * 8;
  bf16_t* bsd = Bs + tid * 8;
  const int nk = KD >> 5;
  for (int kt = 0; kt < nk; kt++) {
    async_copy16(ag, asd);
    async_copy16(ag + (size_t)64 * K, asd + 64 * 32);
    async_copy16(bg, bsd);
    async_copy16(bg + (size_t)64 * K, bsd + 64 * 32);
    ag += 32; bg += 32;
    __syncthreads();
    bf16x8 af[4], bf[4];
#pragma unroll
    for (int mt = 0; mt < 4; mt++)
      af[mt] = *(const bf16x8*)(As + (wi * 64 + mt * 16 + l16) * 32 + quad * 8);
#pragma unroll
    for (int nt = 0; nt < 4; nt++)
      bf[nt] = *(const bf16x8*)(Bs + (wj * 64 + nt * 16 + l16) * 32 + quad * 8);
#pragma unroll
    for (int mt = 0; mt < 4; mt++)
#pragma unroll
      for (int nt = 0; nt < 4; nt++)
        acc[mt][nt] = __builtin_amdgcn_mfma_f32_16x16x32_bf16(af[mt], bf[nt], acc[mt][nt], 0, 0, 0);
    __syncthreads();
  }
  float* C = z ? C1 : C0;
#pragma unroll
  for (int nt = 0; nt < 4; nt++) {
    size_t col = n0 + wj * 64 + nt * 16 + l16;
#pragma unroll
    for (int mt = 0; mt < 4; mt++) {
      size_t row = m0 + wi * 64 + mt * 16 + quad * 4;
#pragma unroll
      for (int r = 0; r < 4; r++) C[(row + r) * N + col] = acc[mt][nt][r];
    }
  }
}

// ---------------- 256x256 8-phase GEMM: C = A @ Bt^T + bias ----------------
// (verified round-3 kernel, unchanged)
template <typename OutT>
__global__ __launch_bounds__(512, 2) void gemm256(const bf16_t* __restrict__ A,
                                                  const bf16_t* __restrict__ Bt,
                                                  const float* __restrict__ bias,
                                                  OutT* __restrict__ C, int M, int N, int K) {
  extern __shared__ char smem_raw[];
  bf16_t* As_ = (bf16_t*)smem_raw;          // 2 slots x 2 kh x 8192 el = 64 KiB
  bf16_t* Bs_ = As_ + 32768;                // same, 64 KiB

  const int tid = threadIdx.x;
  const int lane = tid & 63;
  const int wv = tid >> 6;
  const int wr = wv >> 2, wc = wv & 3;
  const int quad = lane >> 4, l16 = lane & 15;

  const int bid = blockIdx.x;
  const int g = (bid & 7) * 32 + (bid >> 3);
  const size_t m0 = (size_t)(g >> 3) * 256;
  const size_t n0 = (size_t)(g & 7) * 256;

  auto mkrow = [](int s) { int rp = s >> 3; int Cc = (s & 7) ^ (rp & 7); return rp * 2 + (Cc >> 2); };
  auto mkkc  = [](int s) { int rp = s >> 3; int Cc = (s & 7) ^ (rp & 7); return (Cc & 3) * 8; };
  const bf16_t* pA0 = A  + (size_t)(m0 + mkrow(tid)) * K + mkkc(tid);
  const bf16_t* pA1 = A  + (size_t)(m0 + mkrow(tid + 512)) * K + mkkc(tid + 512);
  const bf16_t* pB0 = Bt + (size_t)(n0 + mkrow(tid)) * K + mkkc(tid);
  const bf16_t* pB1 = Bt + (size_t)(n0 + mkrow(tid + 512)) * K + mkkc(tid + 512);

#define STAGE_A(SLOT, KH, KT) do { \
    async_copy16(pA0 + (size_t)(KT) * 64 + (KH) * 32, As_ + (SLOT) * 16384 + (KH) * 8192 + tid * 8); \
    async_copy16(pA1 + (size_t)(KT) * 64 + (KH) * 32, As_ + (SLOT) * 16384 + (KH) * 8192 + (tid + 512) * 8); \
  } while (0)
#define STAGE_B(SLOT, KH, KT) do { \
    async_copy16(pB0 + (size_t)(KT) * 64 + (KH) * 32, Bs_ + (SLOT) * 16384 + (KH) * 8192 + tid * 8); \
    async_copy16(pB1 + (size_t)(KT) * 64 + (KH) * 32, Bs_ + (SLOT) * 16384 + (KH) * 8192 + (tid + 512) * 8); \
  } while (0)

  int aoffs[8], boffs[4];
#pragma unroll
  for (int mi = 0; mi < 8; mi++) {
    int row = wr * 128 + mi * 16 + l16;
    int rp = row >> 1, Cc = (row & 1) * 4 + quad;
    aoffs[mi] = rp * 64 + (Cc ^ (rp & 7)) * 8;
  }
#pragma unroll
  for (int ni = 0; ni < 4; ni++) {
    int row = wc * 64 + ni * 16 + l16;
    int rp = row >> 1, Cc = (row & 1) * 4 + quad;
    boffs[ni] = rp * 64 + (Cc ^ (rp & 7)) * 8;
  }

  f32x4 acc[8][4] = {};
  bf16x8 afr[8], b0, b1;

#define LOAD_A(SLOT, KS) do { _Pragma("unroll") \
    for (int mi = 0; mi < 8; mi++) afr[mi] = *(const bf16x8*)(As_ + (SLOT) * 16384 + (KS) * 8192 + aoffs[mi]); \
  } while (0)
#define LOAD_B2(SLOT, KS, NF0) do { \
    b0 = *(const bf16x8*)(Bs_ + (SLOT) * 16384 + (KS) * 8192 + boffs[NF0]); \
    b1 = *(const bf16x8*)(Bs_ + (SLOT) * 16384 + (KS) * 8192 + boffs[(NF0) + 1]); \
  } while (0)
#define MFMA16(NF0) do { __builtin_amdgcn_s_setprio(1); _Pragma("unroll") \
    for (int mi = 0; mi < 8; mi++) { \
      acc[mi][NF0] = __builtin_amdgcn_mfma_f32_16x16x32_bf16(afr[mi], b0, acc[mi][NF0], 0, 0, 0); \
      acc[mi][(NF0) + 1] = __builtin_amdgcn_mfma_f32_16x16x32_bf16(afr[mi], b1, acc[mi][(NF0) + 1], 0, 0, 0); \
    } __builtin_amdgcn_s_setprio(0); } while (0)

  const int NI = K >> 7;

  STAGE_A(0, 0, 0); STAGE_B(0, 0, 0);
  STAGE_A(0, 1, 0); STAGE_B(0, 1, 0);
  STAGE_A(1, 0, 1); STAGE_B(1, 0, 1);
  VM0;
  SB; BAR; SB;

#pragma unroll 1
  for (int j = 0; j < NI; j++) {
    const int last = (j == NI - 1);
    LOAD_A(0, 0); LOAD_B2(0, 0, 0);
    STAGE_A(1, 1, 2 * j + 1);
    SB; BAR; LGKM0; SB; MFMA16(0); SB; BAR;
    LOAD_B2(0, 0, 2);
    STAGE_B(1, 1, 2 * j + 1);
    SB; BAR; LGKM0; SB; MFMA16(2); SB; BAR;
    LOAD_A(0, 1); LOAD_B2(0, 1, 0);
    if (!last) STAGE_A(0, 0, 2 * j + 2);
    SB; BAR; LGKM0; SB; MFMA16(0); SB; BAR;
    LOAD_B2(0, 1, 2);
    if (!last) STAGE_B(0, 0, 2 * j + 2);
    SB;
    if (!last) { asm volatile("s_waitcnt vmcnt(4)" ::: "memory"); }
    else       { VM0; }
    BAR; LGKM0; SB; MFMA16(2); SB; BAR;
    LOAD_A(1, 0); LOAD_B2(1, 0, 0);
    if (!last) STAGE_A(0, 1, 2 * j + 2);
    SB; BAR; LGKM0; SB; MFMA16(0); SB; BAR;
    LOAD_B2(1, 0, 2);
    if (!last) STAGE_B(0, 1, 2 * j + 2);
    SB; BAR; LGKM0; SB; MFMA16(2); SB; BAR;
    LOAD_A(1, 1); LOAD_B2(1, 1, 0);
    if (!last) STAGE_A(1, 0, 2 * j + 3);
    SB; BAR; LGKM0; SB; MFMA16(0); SB; BAR;
    LOAD_B2(1, 1, 2);
    if (!last) STAGE_B(1, 0, 2 * j + 3);
    SB;
    if (!last) { asm volatile("s_waitcnt vmcnt(4)" ::: "memory"); }
    else       { VM0; }
    BAR; LGKM0; SB; MFMA16(2); SB; BAR;
  }

#pragma unroll
  for (int ni = 0; ni < 4; ni++) {
    size_t col = n0 + wc * 64 + ni * 16 + l16;
    float bb = bias[col];
#pragma unroll
    for (int mi = 0; mi < 8; mi++) {
      size_t row = m0 + wr * 128 + mi * 16 + quad * 4;
#pragma unroll
      for (int r = 0; r < 4; r++) store_out(&C[(row + r) * N + col], acc[mi][ni][r] + bb);
    }
  }
#undef STAGE_A
#undef STAGE_B
#undef LOAD_A
#undef LOAD_B2
#undef MFMA16
}

// ---------------- RoPE ----------------
// freq_i = 10000^(-2i/128) = exp(-i * ln(10000)/64)
#define ROPE_C 0.14391156831212787f
// attention scale folded into Q: 1/sqrt(128) * log2(e)  (softmax via exp2)
#define ATT_SCALE 0.1275174462517703f

// fused: sum split-K partials + bias, rope K -> kh/kbf, V -> vh (blocks 0..2047)
//        sum partials + bias, transpose V -> vT                (blocks 2048..3071)
__global__ void rope_kv_tv(const float* __restrict__ p0, const float* __restrict__ p1,
                           const float* __restrict__ bk, const float* __restrict__ bv,
                           float* __restrict__ kh, float* __restrict__ vh,
                           bf16_t* __restrict__ kbf, bf16_t* __restrict__ vT) {
  int bid = blockIdx.x;
  if (bid < 2048) {
    int idx = bid * 256 + threadIdx.x;  // one per K-pair
    int t = idx >> 6;
    int i = idx & 63;
    int s = t & (SEQ - 1);
    const float* b0 = p0 + (size_t)t * 256;
    const float* b1 = p1 + (size_t)t * 256;
    float x1 = b0[2 * i] + b1[2 * i] + bk[2 * i];
    float x2 = b0[2 * i + 1] + b1[2 * i + 1] + bk[2 * i + 1];
    float fr = __expf(-(float)i * ROPE_C);
    float ang = (float)s * fr;
    float sn, cs; __sincosf(ang, &sn, &cs);
    float k1 = x1 * cs - x2 * sn, k2 = x1 * sn + x2 * cs;
    size_t o = (size_t)t * HD + 2 * i;
    kh[o] = k1; kh[o + 1] = k2;
    kbf[o] = (bf16_t)k1; kbf[o + 1] = (bf16_t)k2;
    vh[o] = b0[128 + 2 * i] + b1[128 + 2 * i] + bv[2 * i];
    vh[o + 1] = b0[128 + 2 * i + 1] + b1[128 + 2 * i + 1] + bv[2 * i + 1];
  } else {
    __shared__ float tile[32][33];
    int t = bid - 2048;                 // 64 x 4 x 4
    int s0 = (t & 63) * 32, d0 = ((t >> 6) & 3) * 32, b = t >> 8;
    int tx = threadIdx.x & 31, ty = threadIdx.x >> 5;
    for (int i = ty; i < 32; i += 8) {
      size_t ix = (size_t)(b * SEQ + s0 + i) * 256 + 128 + d0 + tx;
      tile[i][tx] = p0[ix] + p1[ix] + bv[d0 + tx];
    }
    __syncthreads();
    for (int i = ty; i < 32; i += 8)
      vT[(size_t)b * HD * SEQ + (size_t)(d0 + i) * SEQ + s0 + tx] = (bf16_t)tile[tx][i];
  }
}

// ---------------- flash attention (causal MQA), S^T formulation ----------------
// (round-4/6 verified kernel, verbatim: 123.5 us, absmax 0.015625)
__global__ __launch_bounds__(256, 2) void flash_attn_kernel(const bf16_t* __restrict__ Q,
                                                            const bf16_t* __restrict__ Kb,
                                                            const bf16_t* __restrict__ VT,
                                                            bf16_t* __restrict__ O) {
  __shared__ bf16_t Ks[2][64 * 128];   // row=k-token (64), 16 chunks of 8, XOR-swizzled
  __shared__ bf16_t Vs[2][64 * 128];   // row=d (128), 8 chunks of 8, XOR-swizzled
  const int tid = threadIdx.x;
  const int lane = tid & 63;
  const int wv = tid >> 6;
  const int quad = lane >> 4, l16 = lane & 15;
  const int pr = blockIdx.x, h = blockIdx.y, b = blockIdx.z;

  const bf16_t* kbase = Kb + (size_t)b * SEQ * HD;
  const bf16_t* vbase = VT + (size_t)b * HD * SEQ;

  int cur = 0;
  // prologue: stage tile 0 into buffer 0, drain, publish
#pragma unroll
  for (int i = 0; i < 4; i++) {
    int p = i * 256 + tid;
    int kr = p >> 4, kc = (p & 15) ^ (kr & 15);
    async_copy16(kbase + (size_t)kr * HD + kc * 8, &Ks[0][p * 8]);
    int vr = p >> 3, vc = (p & 7) ^ (vr & 7);
    async_copy16(vbase + (size_t)vr * SEQ + vc * 8, &Vs[0][p * 8]);
  }
  VM0;
  SB; BAR; SB;

#pragma unroll 1
  for (int ph = 0; ph < 2; ph++) {
    const int qt = ph ? pr : 15 - pr;   // block-uniform
    const int nkt = 2 * qt + 2;

    // Q fragments with fused RoPE + scale. Element j of qf[nt][ks] is
    // Q[qrow, h*128 + ks*32 + quad*8 + j]; rope pairs are (j=2jj, 2jj+1),
    // i = ks*16 + quad*4 + jj, position s = seq row.
    bf16x8 qf[2][4];
#pragma unroll
    for (int nt = 0; nt < 2; nt++) {
      const int srow = qt * 128 + wv * 32 + nt * 16 + l16;
      size_t qrow = (size_t)b * SEQ + srow;
      const bf16_t* qp = Q + qrow * DM + h * HD + quad * 8;
#pragma unroll
      for (int ks = 0; ks < 4; ks++) {
        union { uint4 u4; ushort us[8]; } u;
        u.u4 = *(const uint4*)(qp + ks * 32);
        union { ushort us[8]; bf16x8 v; } w;
#pragma unroll
        for (int jj = 0; jj < 4; jj++) {
          float x1 = __uint_as_float((uint32_t)u.us[2 * jj] << 16);
          float x2 = __uint_as_float((uint32_t)u.us[2 * jj + 1] << 16);
          int i = ks * 16 + quad * 4 + jj;
          float fr = __expf(-(float)i * ROPE_C);
          float ang = (float)srow * fr;
          float sn, cs; __sincosf(ang, &sn, &cs);
          w.us[2 * jj]     = bf16_rne((x1 * cs - x2 * sn) * ATT_SCALE);
          w.us[2 * jj + 1] = bf16_rne((x1 * sn + x2 * cs) * ATT_SCALE);
        }
        qf[nt][ks] = w.v;
      }
    }

    f32x4 oacc[8][2] = {};
    float l2[2] = {0.f, 0.f};

#pragma unroll 1
    for (int kt = 0; kt < nkt; kt++) {
      // stage next tile into buf[cur^1] (issue-first; lands during compute)
      const int has_next = !(ph == 1 && kt == nkt - 1);
      if (has_next) {
        const int k0n = (kt + 1 < nkt) ? (kt + 1) * 64 : 0;  // phase switch restarts at k=0
        bf16_t* kd = &Ks[cur ^ 1][0];
        bf16_t* vd = &Vs[cur ^ 1][0];
#pragma unroll
        for (int i = 0; i < 4; i++) {
          int p = i * 256 + tid;
          int kr = p >> 4, kc = (p & 15) ^ (kr & 15);
          async_copy16(kbase + (size_t)(k0n + kr) * HD + kc * 8, kd + p * 8);
          int vr = p >> 3, vc = (p & 7) ^ (vr & 7);
          async_copy16(vbase + (size_t)vr * SEQ + k0n + vc * 8, vd + p * 8);
        }
      }
      SB;

      const bf16_t* KsC = &Ks[cur][0];
      const bf16_t* VsC = &Vs[cur][0];

      // S^T[k][q] = K Q^T
      f32x4 sa[4][2] = {};
#pragma unroll
      for (int ks = 0; ks < 4; ks++) {
        bf16x8 ak[4];
#pragma unroll
        for (int mt = 0; mt < 4; mt++) {
          int row = mt * 16 + l16;
          int c = (ks * 4 + quad) ^ l16;
          ak[mt] = *(const bf16x8*)(KsC + (row * 16 + c) * 8);
        }
        __builtin_amdgcn_s_setprio(1);
#pragma unroll
        for (int mt = 0; mt < 4; mt++)
#pragma unroll
          for (int nt = 0; nt < 2; nt++)
            sa[mt][nt] = __builtin_amdgcn_mfma_f32_16x16x32_bf16(ak[mt], qf[nt][ks], sa[mt][nt], 0, 0, 0);
        __builtin_amdgcn_s_setprio(0);
      }

      // causal mask — only the 2 diagonal tiles (uniform branch)
      if (kt >= 2 * qt) {
        const int k0c = kt * 64;
#pragma unroll
        for (int mt = 0; mt < 4; mt++)
#pragma unroll
          for (int nt = 0; nt < 2; nt++) {
            int kg0 = k0c + mt * 16 + quad * 4;
            int qg = qt * 128 + wv * 32 + nt * 16 + l16;
#pragma unroll
            for (int r = 0; r < 4; r++)
              if (kg0 + r > qg) sa[mt][nt][r] = -INFINITY;
          }
      }

      // shift-free softmax + in-register P->bf16 B-fragment assembly
      bf16x8 bp[2][2];
#pragma unroll
      for (int nt = 0; nt < 2; nt++) {
        float rs = 0.f;
#pragma unroll
        for (int mt = 0; mt < 4; mt++)
#pragma unroll
          for (int r = 0; r < 4; r++) {
            float pv = exp2f(sa[mt][nt][r]);
            sa[mt][nt][r] = pv;
            rs += pv;
          }
        {
          float a0 = rs, a1 = rs;
          asm("v_permlane16_swap_b32 %0, %1" : "+v"(a0), "+v"(a1));
          rs = a0 + a1;
          float c0 = rs, c1 = rs;
          asm("v_permlane32_swap_b32 %0, %1" : "+v"(c0), "+v"(c1));
          rs = c0 + c1;
        }
        l2[nt] += rs;

        uint32_t d0[4], d1[4];
#pragma unroll
        for (int m = 0; m < 4; m++) {
          asm("v_cvt_pk_bf16_f32 %0, %1, %2" : "=v"(d0[m]) : "v"(sa[m][nt][0]), "v"(sa[m][nt][1]));
          asm("v_cvt_pk_bf16_f32 %0, %1, %2" : "=v"(d1[m]) : "v"(sa[m][nt][2]), "v"(sa[m][nt][3]));
        }
#pragma unroll
        for (int ks = 0; ks < 2; ks++) {
          uint32_t w0 = d0[2 * ks], w2 = d0[2 * ks + 1];
          uint32_t w1 = d1[2 * ks], w3 = d1[2 * ks + 1];
          asm("v_permlane32_swap_b32 %0, %1" : "+v"(w0), "+v"(w2));
          asm("v_permlane16_swap_b32 %0, %1" : "+v"(w0), "+v"(w2));
          asm("v_permlane32_swap_b32 %0, %1" : "+v"(w1), "+v"(w3));
          asm("v_permlane16_swap_b32 %0, %1" : "+v"(w1), "+v"(w3));
          union { uint32_t u[4]; bf16x8 v; } pk_;
          pk_.u[0] = w0; pk_.u[1] = w1; pk_.u[2] = w2; pk_.u[3] = w3;
          bp[nt][ks] = pk_.v;
        }
      }

      // O^T += V^T P^T
#pragma unroll
      for (int ks = 0; ks < 2; ks++)
#pragma unroll
        for (int dm = 0; dm < 8; dm++) {
          int row = dm * 16 + l16;
          int c = (ks * 4 + quad) ^ (row & 7);
          bf16x8 av = *(const bf16x8*)(VsC + (row * 8 + c) * 8);
          __builtin_amdgcn_s_setprio(1);
#pragma unroll
          for (int nt = 0; nt < 2; nt++)
            oacc[dm][nt] = __builtin_amdgcn_mfma_f32_16x16x32_bf16(av, bp[nt][ks], oacc[dm][nt], 0, 0, 0);
          __builtin_amdgcn_s_setprio(0);
        }

      // end-of-iter: all LDS reads done, staged tile landed, publish
      LGKM0;
      VM0;
      SB; BAR; SB;
      cur ^= 1;
    }

    float inv[2];
#pragma unroll
    for (int nt = 0; nt < 2; nt++) inv[nt] = 1.f / l2[nt];
#pragma unroll
    for (int dm = 0; dm < 8; dm++)
#pragma unroll
      for (int nt = 0; nt < 2; nt++) {
        size_t row = (size_t)b * SEQ + qt * 128 + wv * 32 + nt * 16 + l16;
        size_t col = (size_t)h * HD + dm * 16 + quad * 4;
        union { ushort4 u; bf16_t bb[4]; } pk;
#pragma unroll
        for (int r = 0; r < 4; r++) pk.bb[r] = (bf16_t)(oacc[dm][nt][r] * inv[nt]);
        *(ushort4*)(O + row * DM + col) = pk.u;
      }
  }
}

// ---------------- launch ----------------

extern "C" void kernel_launch(void* const* d_in, const int* in_sizes, int n_in,
                              void* d_out, int out_size, void* d_ws, size_t ws_size,
                              hipStream_t stream) {
  const float* x  = (const float*)d_in[0];
  const float* wq = (const float*)d_in[1];
  const float* bq = (const float*)d_in[2];
  const float* wk = (const float*)d_in[3];
  const float* bk = (const float*)d_in[4];
  const float* wv = (const float*)d_in[5];
  const float* bv = (const float*)d_in[6];
  const float* wo = (const float*)d_in[7];
  const float* bo = (const float*)d_in[8];
  char* ws = (char*)d_ws;

  bf16_t* xbf  = (bf16_t*)(ws);                 // 33.5 MB  (reused as attn later)
  bf16_t* qbf  = (bf16_t*)(ws + 33554432ull);   // 33.5 MB
  bf16_t* wqT  = (bf16_t*)(ws + 67108864ull);   // 8.4 MB (reused as KV partial 1)
  bf16_t* woT  = (bf16_t*)(ws + 75497472ull);   // 8.4 MB
  bf16_t* wkvT = (bf16_t*)(ws + 83886080ull);   // 1 MB
  float*  kvf  = (float* )(ws + 84934656ull);   // 8.4 MB (KV partial 0)
  bf16_t* kbf  = (bf16_t*)(ws + 93323264ull);   // 2 MB
  bf16_t* vT   = (bf16_t*)(ws + 95420416ull);   // 2 MB
  bf16_t* attn = xbf;   // alias: x_bf16 dead after the two input GEMMs
  float*  kvp1 = (float*)wqT;  // alias: wqT dead after the Q-projection GEMM

  float* out = (float*)d_out;
  float* kh  = out + 16777216ull;
  float* vh  = kh + 1048576ull;

  static bool attr_done = false;
  if (!attr_done) {
    hipFuncSetAttribute((const void*)gemm256<bf16_t>, hipFuncAttributeMaxDynamicSharedMemorySize, 131072);
    hipFuncSetAttribute((const void*)gemm256<float>,  hipFuncAttributeMaxDynamicSharedMemorySize, 131072);
    attr_done = true;
  }

  preprocess<<<25088, 256, 0, stream>>>(x, xbf, wq, wo, wqT, woT, wk, wv, wkvT);

  gemm256<bf16_t><<<256, 512, 131072, stream>>>(xbf, wqT, bq, qbf, 8192, 2048, 2048);
  gemm_kv_split<<<dim3(64, 2, 2), 256, 0, stream>>>(xbf, wkvT, kvf, kvp1, 8192, 256, 2048, 1024);

  rope_kv_tv<<<3072, 256, 0, stream>>>(kvf, kvp1, bk, bv, kh, vh, kbf, vT);

  flash_attn_kernel<<<dim3(8, 16, 4), 256, 0, stream>>>(qbf, kbf, vT, attn);

  gemm256<float><<<256, 512, 131072, stream>>>(attn, woT, bo, out, 8192, 2048, 2048);
}